// Round 2
// baseline (4573.962 us; speedup 1.0000x reference)
//
#include <hip/hip_runtime.h>

#define EMB   64
#define NCON  50000
#define NVAR  100000
#define NEDGE 1600000
#define EPSLN 1e-5f

__device__ __forceinline__ float wsum64(float x) {
#pragma unroll
    for (int off = 32; off > 0; off >>= 1)
        x += __shfl_xor(x, off, 64);
    return x;
}

// ---------------- CSR build ----------------

__global__ __launch_bounds__(256) void hist_kernel(const int* __restrict__ dst,
                                                   int* __restrict__ hist, int E) {
    int i = blockIdx.x * blockDim.x + threadIdx.x;
    for (; i < E; i += gridDim.x * blockDim.x)
        atomicAdd(&hist[dst[i]], 1);
}

// single wave; exclusive scan of hist[0..N) -> rowptr[0..N], cursor[0..N)
// (cursor may alias hist: reads of a chunk complete before its writes)
__global__ void scan_wave_kernel(const int* __restrict__ hist, int* __restrict__ rowptr,
                                 int* __restrict__ cursor, int N) {
    const int lane = threadIdx.x;
    int carry = 0;
    for (int base = 0; base < N; base += 64) {
        const int i = base + lane;
        int val = (i < N) ? hist[i] : 0;
        int incl = val;
#pragma unroll
        for (int off = 1; off < 64; off <<= 1) {
            int t = __shfl_up(incl, off, 64);
            if (lane >= off) incl += t;
        }
        const int excl = incl - val + carry;
        if (i < N) { rowptr[i] = excl; cursor[i] = excl; }
        carry += __shfl(incl, 63, 64);
    }
    if (lane == 0) rowptr[N] = carry;
}

__global__ __launch_bounds__(256) void scatter_kernel(
        const int* __restrict__ dst, const int* __restrict__ src,
        const float* __restrict__ ef, int* __restrict__ cursor,
        int* __restrict__ srcp, float* __restrict__ efp, int E) {
    int i = blockIdx.x * blockDim.x + threadIdx.x;
    for (; i < E; i += gridDim.x * blockDim.x) {
        const int slot = atomicAdd(&cursor[dst[i]], 1);
        srcp[slot] = src[i];
        efp[slot]  = ef[i];
    }
}

// ---------------- node linear ----------------

// Y[n][i] = (b?b[i]:0) + sum_j X[n][j] * W[i*wstride + j]   (wave per node, lane = i)
__global__ __launch_bounds__(256) void lin_kernel(
        const float* __restrict__ X, const float* __restrict__ W, int wstride,
        const float* __restrict__ b, float* __restrict__ Y, int N) {
    __shared__ float xbuf[4][EMB];
    const int wv = threadIdx.x >> 6;
    const int lane = threadIdx.x & 63;
    float w[EMB];
#pragma unroll
    for (int j4 = 0; j4 < 16; ++j4) {
        float4 t = *(const float4*)(W + lane * wstride + j4 * 4);
        w[4*j4+0] = t.x; w[4*j4+1] = t.y; w[4*j4+2] = t.z; w[4*j4+3] = t.w;
    }
    const float bias = b ? b[lane] : 0.0f;
    const int nW = gridDim.x * 4;
    for (int n = blockIdx.x * 4 + wv; n < N; n += nW) {
        xbuf[wv][lane] = X[(size_t)n * EMB + lane];
        float acc = bias;
#pragma unroll
        for (int j4 = 0; j4 < 16; ++j4) {
            float4 xv = *(const float4*)&xbuf[wv][j4 * 4];
            acc += xv.x * w[4*j4+0];
            acc += xv.y * w[4*j4+1];
            acc += xv.z * w[4*j4+2];
            acc += xv.w * w[4*j4+3];
        }
        Y[(size_t)n * EMB + lane] = acc;
    }
}

// ---------------- edge stage: CSR, wave per dst node, register accumulate ----------------

__global__ __launch_bounds__(256, 4) void edge_csr_kernel(
        const int* __restrict__ rowptr, const int* __restrict__ srcp,
        const float* __restrict__ efp,
        const float* __restrict__ RL, const float* __restrict__ LL,
        const float* __restrict__ Wecol, const float* __restrict__ g1,
        const float* __restrict__ b1,
        const float* __restrict__ Wf, const float* __restrict__ bfp,
        float* __restrict__ AGG, int Nr) {
    __shared__ float hbuf[4][EMB];
    const int wv = threadIdx.x >> 6;
    const int lane = threadIdx.x & 63;
    float w[EMB];
#pragma unroll
    for (int j4 = 0; j4 < 16; ++j4) {
        float4 t = *(const float4*)(Wf + lane * EMB + j4 * 4);
        w[4*j4+0] = t.x; w[4*j4+1] = t.y; w[4*j4+2] = t.z; w[4*j4+3] = t.w;
    }
    const float we  = Wecol[lane];
    const float g   = g1[lane];
    const float bb  = b1[lane];
    const float bf_ = bfp[lane];
    const int nW = gridDim.x * 4;
    for (int n = blockIdx.x * 4 + wv; n < Nr; n += nW) {
        const int beg = rowptr[n];
        const int end = rowptr[n + 1];
        const float rl = RL[(size_t)n * EMB + lane];
        float acc = 0.0f;
        if (beg < end) {
            // software pipeline the src gather
            float f  = efp[beg];
            float ll = LL[(size_t)srcp[beg] * EMB + lane];
            for (int idx = beg; idx < end; ++idx) {
                float f_n = 0.0f, ll_n = 0.0f;
                if (idx + 1 < end) {
                    f_n  = efp[idx + 1];
                    ll_n = LL[(size_t)srcp[idx + 1] * EMB + lane];
                }
                float h = rl + ll + f * we;
                const float s1 = wsum64(h);
                const float s2 = wsum64(h * h);
                const float m   = s1 * (1.0f / EMB);
                const float var = s2 * (1.0f / EMB) - m * m;
                float hn = fmaxf((h - m) * rsqrtf(var + EPSLN) * g + bb, 0.0f);
                hbuf[wv][lane] = hn;
#pragma unroll
                for (int j4 = 0; j4 < 16; ++j4) {
                    float4 xv = *(const float4*)&hbuf[wv][j4 * 4];
                    acc += xv.x * w[4*j4+0];
                    acc += xv.y * w[4*j4+1];
                    acc += xv.z * w[4*j4+2];
                    acc += xv.w * w[4*j4+3];
                }
                f = f_n; ll = ll_n;
            }
        }
        acc += (float)(end - beg) * bf_;   // per-edge bias folded: sum_e bf = deg*bf
        AGG[(size_t)n * EMB + lane] = acc;
    }
}

// ---------------- legacy atomic edge path (ws fallback) ----------------

__global__ __launch_bounds__(256) void edge_kernel(
        const int* __restrict__ dst, const int* __restrict__ src,
        const float* __restrict__ ef,
        const float* __restrict__ RL, const float* __restrict__ LL,
        const float* __restrict__ Wecol, const float* __restrict__ g1,
        const float* __restrict__ b1,
        const float* __restrict__ Wf, const float* __restrict__ bfp,
        float* __restrict__ AGG) {
    __shared__ float hbuf[4][EMB];
    const int wv = threadIdx.x >> 6;
    const int lane = threadIdx.x & 63;
    float w[EMB];
#pragma unroll
    for (int j4 = 0; j4 < 16; ++j4) {
        float4 t = *(const float4*)(Wf + lane * EMB + j4 * 4);
        w[4*j4+0] = t.x; w[4*j4+1] = t.y; w[4*j4+2] = t.z; w[4*j4+3] = t.w;
    }
    const float we = Wecol[lane];
    const float g  = g1[lane];
    const float bb = b1[lane];
    const float bf_ = bfp[lane];
    const int nW = gridDim.x * 4;
    for (int e = blockIdx.x * 4 + wv; e < NEDGE; e += nW) {
        const int d = dst[e];
        const int s = src[e];
        const float f = ef[e];
        float h = RL[(size_t)d * EMB + lane] + LL[(size_t)s * EMB + lane] + f * we;
        const float s1 = wsum64(h);
        const float s2 = wsum64(h * h);
        const float m   = s1 * (1.0f / EMB);
        const float var = s2 * (1.0f / EMB) - m * m;
        float hn = fmaxf((h - m) * rsqrtf(var + EPSLN) * g + bb, 0.0f);
        hbuf[wv][lane] = hn;
        float acc = bf_;
#pragma unroll
        for (int j4 = 0; j4 < 16; ++j4) {
            float4 xv = *(const float4*)&hbuf[wv][j4 * 4];
            acc += xv.x * w[4*j4+0];
            acc += xv.y * w[4*j4+1];
            acc += xv.z * w[4*j4+2];
            acc += xv.w * w[4*j4+3];
        }
        atomicAdd(&AGG[(size_t)d * EMB + lane], acc);
    }
}

// ---------------- output MLP ----------------

__global__ __launch_bounds__(256) void out_kernel(
        const float* __restrict__ AGG, const float* __restrict__ RB,
        float* __restrict__ right,
        const float* __restrict__ g2, const float* __restrict__ b2,
        const float* __restrict__ Wo1, const float* __restrict__ Wo2,
        const float* __restrict__ bo2, int N) {
    __shared__ float zbuf[4][EMB];
    __shared__ float obuf[4][EMB];
    const int wv = threadIdx.x >> 6;
    const int lane = threadIdx.x & 63;
    float w1[EMB], w2[EMB];
#pragma unroll
    for (int j4 = 0; j4 < 16; ++j4) {
        float4 t1 = *(const float4*)(Wo1 + lane * (2 * EMB) + j4 * 4);
        w1[4*j4+0] = t1.x; w1[4*j4+1] = t1.y; w1[4*j4+2] = t1.z; w1[4*j4+3] = t1.w;
        float4 t2 = *(const float4*)(Wo2 + lane * EMB + j4 * 4);
        w2[4*j4+0] = t2.x; w2[4*j4+1] = t2.y; w2[4*j4+2] = t2.z; w2[4*j4+3] = t2.w;
    }
    const float g  = g2[lane];
    const float bb = b2[lane];
    const float bo = bo2[lane];
    const int nW = gridDim.x * 4;
    for (int n = blockIdx.x * 4 + wv; n < N; n += nW) {
        const float a = AGG[(size_t)n * EMB + lane];
        const float s1 = wsum64(a);
        const float s2 = wsum64(a * a);
        const float m   = s1 * (1.0f / EMB);
        const float var = s2 * (1.0f / EMB) - m * m;
        const float z = (a - m) * rsqrtf(var + EPSLN) * g + bb;
        zbuf[wv][lane] = z;
        float acc = RB[(size_t)n * EMB + lane];
#pragma unroll
        for (int j4 = 0; j4 < 16; ++j4) {
            float4 zv = *(const float4*)&zbuf[wv][j4 * 4];
            acc += zv.x * w1[4*j4+0];
            acc += zv.y * w1[4*j4+1];
            acc += zv.z * w1[4*j4+2];
            acc += zv.w * w1[4*j4+3];
        }
        const float o = fmaxf(acc, 0.0f);
        obuf[wv][lane] = o;
        float acc2 = bo;
#pragma unroll
        for (int j4 = 0; j4 < 16; ++j4) {
            float4 ov = *(const float4*)&obuf[wv][j4 * 4];
            acc2 += ov.x * w2[4*j4+0];
            acc2 += ov.y * w2[4*j4+1];
            acc2 += ov.z * w2[4*j4+2];
            acc2 += ov.w * w2[4*j4+3];
        }
        right[(size_t)n * EMB + lane] += acc2;
    }
}

extern "C" void kernel_launch(void* const* d_in, const int* in_sizes, int n_in,
                              void* d_out, int out_size, void* d_ws, size_t ws_size,
                              hipStream_t stream) {
    const float* cf  = (const float*)d_in[0];
    const float* vfp = (const float*)d_in[1];
    const int*   ei  = (const int*)d_in[2];
    const float* ef  = (const float*)d_in[3];
    const float* Wl  = (const float*)d_in[4];
    const float* bl  = (const float*)d_in[5];
    const float* We  = (const float*)d_in[6];
    const float* Wr  = (const float*)d_in[7];
    const float* g1  = (const float*)d_in[8];
    const float* b1  = (const float*)d_in[9];
    const float* Wf  = (const float*)d_in[10];
    const float* bfp = (const float*)d_in[11];
    const float* g2  = (const float*)d_in[12];
    const float* b2  = (const float*)d_in[13];
    const float* Wo1 = (const float*)d_in[14];
    const float* bo1 = (const float*)d_in[15];
    const float* Wo2 = (const float*)d_in[16];
    const float* bo2 = (const float*)d_in[17];

    float* c = (float*)d_out;
    float* v = c + (size_t)NCON * EMB;
    hipMemcpyAsync(c, cf,  (size_t)NCON * EMB * sizeof(float), hipMemcpyDeviceToDevice, stream);
    hipMemcpyAsync(v, vfp, (size_t)NVAR * EMB * sizeof(float), hipMemcpyDeviceToDevice, stream);

    float* wsf = (float*)d_ws;
    size_t off = 0;
    float* AGG = wsf + off; off += (size_t)NVAR * EMB;   // 6.4M
    float* RL  = wsf + off; off += (size_t)NVAR * EMB;   // 6.4M (also RB)
    float* LL  = wsf + off; off += (size_t)NVAR * EMB;   // 6.4M
    int*   ptrC  = (int*)(wsf + off); off += 50004;
    int*   curC  = (int*)(wsf + off); off += 50004;      // hist then cursor (aliased)
    int*   ptrV  = (int*)(wsf + off); off += 100004;
    int*   curV  = (int*)(wsf + off); off += 100004;
    int*   srcpC = (int*)(wsf + off); off += NEDGE;
    float* efpC  = wsf + off;         off += NEDGE;
    int*   srcpV = (int*)(wsf + off); off += NEDGE;
    float* efpV  = wsf + off;         off += NEDGE;
    const bool use_csr = ws_size >= off * sizeof(float);

    const int* ci = ei;
    const int* vi = ei + NEDGE;

    const dim3 blk(256);
    const int NB = 2048;

    if (use_csr) {
        hipMemsetAsync(curC, 0, NCON * sizeof(int), stream);
        hipMemsetAsync(curV, 0, NVAR * sizeof(int), stream);
        hist_kernel<<<1024, blk, 0, stream>>>(ci, curC, NEDGE);
        hist_kernel<<<1024, blk, 0, stream>>>(vi, curV, NEDGE);
        scan_wave_kernel<<<1, 64, 0, stream>>>(curC, ptrC, curC, NCON);
        scan_wave_kernel<<<1, 64, 0, stream>>>(curV, ptrV, curV, NVAR);
        scatter_kernel<<<1024, blk, 0, stream>>>(ci, vi, ef, curC, srcpC, efpC, NEDGE);
        scatter_kernel<<<1024, blk, 0, stream>>>(vi, ci, ef, curV, srcpV, efpV, NEDGE);
    }

    for (int k = 0; k < 4; ++k) {
        const bool v2c = ((k & 1) == 0);
        float* right   = v2c ? c : v;
        float* left    = v2c ? v : c;
        const int Nr   = v2c ? NCON : NVAR;
        const int Nl   = v2c ? NVAR : NCON;
        const int* dst = v2c ? ci : vi;
        const int* src = v2c ? vi : ci;

        // RL = right @ Wl^T + bl ; LL = left @ Wr^T
        lin_kernel<<<NB, blk, 0, stream>>>(right, Wl + (size_t)k * EMB * EMB, EMB,
                                           bl + (size_t)k * EMB, RL, Nr);
        lin_kernel<<<NB, blk, 0, stream>>>(left,  Wr + (size_t)k * EMB * EMB, EMB,
                                           nullptr, LL, Nl);
        if (use_csr) {
            edge_csr_kernel<<<1024, blk, 0, stream>>>(
                v2c ? ptrC : ptrV, v2c ? srcpC : srcpV, v2c ? efpC : efpV,
                RL, LL, We + (size_t)k * EMB,
                g1 + (size_t)k * EMB, b1 + (size_t)k * EMB,
                Wf + (size_t)k * EMB * EMB, bfp + (size_t)k * EMB, AGG, Nr);
        } else {
            hipMemsetAsync(AGG, 0, (size_t)Nr * EMB * sizeof(float), stream);
            edge_kernel<<<NB, blk, 0, stream>>>(dst, src, ef, RL, LL,
                                                We + (size_t)k * EMB,
                                                g1 + (size_t)k * EMB, b1 + (size_t)k * EMB,
                                                Wf + (size_t)k * EMB * EMB,
                                                bfp + (size_t)k * EMB, AGG);
        }
        // RB = right @ Wo1[:,64:128]^T + bo1   (into RL buffer, free after edge stage)
        lin_kernel<<<NB, blk, 0, stream>>>(right, Wo1 + (size_t)k * EMB * 2 * EMB + EMB,
                                           2 * EMB, bo1 + (size_t)k * EMB, RL, Nr);
        out_kernel<<<NB, blk, 0, stream>>>(AGG, RL, right,
                                           g2 + (size_t)k * EMB, b2 + (size_t)k * EMB,
                                           Wo1 + (size_t)k * EMB * 2 * EMB,
                                           Wo2 + (size_t)k * EMB * EMB,
                                           bo2 + (size_t)k * EMB, Nr);
    }
}

// Round 4
// 2449.947 us; speedup vs baseline: 1.8670x; 1.8670x over previous
//
#include <hip/hip_runtime.h>

#define EMB   64
#define NCON  50000
#define NVAR  100000
#define NEDGE 1600000
#define EPSLN 1e-5f

typedef _Float16 half2_t __attribute__((ext_vector_type(2)));

// ---- wave-total (all lanes get sum of 64) : DPP on VALU pipe, no DS ops ----
// dpp_ctrl/row_mask must be ICEs -> template parameters.
template <int CTRL, int RMASK>
__device__ __forceinline__ float dpp_add_f(float x) {
    int m = __builtin_amdgcn_update_dpp(0, __builtin_bit_cast(int, x), CTRL, RMASK, 0xf, true);
    return x + __builtin_bit_cast(float, m);
}
__device__ __forceinline__ float wtotal64(float x) {
    x = dpp_add_f<0x111, 0xf>(x);   // row_shr:1
    x = dpp_add_f<0x112, 0xf>(x);   // row_shr:2
    x = dpp_add_f<0x114, 0xf>(x);   // row_shr:4
    x = dpp_add_f<0x118, 0xf>(x);   // row_shr:8
    x = dpp_add_f<0x142, 0xa>(x);   // row_bcast:15 into rows 1,3
    x = dpp_add_f<0x143, 0xc>(x);   // row_bcast:31 into rows 2,3
    return __builtin_bit_cast(float, __builtin_amdgcn_readlane(__builtin_bit_cast(int, x), 63));
}
template <int CTRL, int RMASK>
__device__ __forceinline__ int dpp_add_i(int x) {
    return x + __builtin_amdgcn_update_dpp(0, x, CTRL, RMASK, 0xf, true);
}
__device__ __forceinline__ int wtotal64_i(int x) {
    x = dpp_add_i<0x111, 0xf>(x);
    x = dpp_add_i<0x112, 0xf>(x);
    x = dpp_add_i<0x114, 0xf>(x);
    x = dpp_add_i<0x118, 0xf>(x);
    x = dpp_add_i<0x142, 0xa>(x);
    x = dpp_add_i<0x143, 0xc>(x);
    return __builtin_amdgcn_readlane(x, 63);
}

__device__ __forceinline__ float dot2f(half2_t a, half2_t b, float c) {
    return __builtin_amdgcn_fdot2(a, b, c, false);
}

// 8 x ds_read_b128 broadcast + 32 x v_dot2_f32_f16 against packed weights
__device__ __forceinline__ float matvec_f16(const _Float16* __restrict__ buf,
                                            const half2_t* __restrict__ wh, float acc) {
    const float4* hp4 = (const float4*)buf;
#pragma unroll
    for (int j4 = 0; j4 < 8; ++j4) {
        float4 t = hp4[j4];
        acc = dot2f(wh[4 * j4 + 0], __builtin_bit_cast(half2_t, t.x), acc);
        acc = dot2f(wh[4 * j4 + 1], __builtin_bit_cast(half2_t, t.y), acc);
        acc = dot2f(wh[4 * j4 + 2], __builtin_bit_cast(half2_t, t.z), acc);
        acc = dot2f(wh[4 * j4 + 3], __builtin_bit_cast(half2_t, t.w), acc);
    }
    return acc;
}

__device__ __forceinline__ void load_w_f16(const float* __restrict__ W, int stride,
                                           int lane, half2_t* wh) {
#pragma unroll
    for (int j4 = 0; j4 < 16; ++j4) {
        float4 t = *(const float4*)(W + (size_t)lane * stride + j4 * 4);
        wh[2 * j4 + 0] = half2_t{(_Float16)t.x, (_Float16)t.y};
        wh[2 * j4 + 1] = half2_t{(_Float16)t.z, (_Float16)t.w};
    }
}

// ---------------- CSR build ----------------

__global__ __launch_bounds__(256) void hist_kernel(const int* __restrict__ dst,
                                                   int* __restrict__ hist, int E) {
    int i = blockIdx.x * blockDim.x + threadIdx.x;
    for (; i < E; i += gridDim.x * blockDim.x)
        atomicAdd(&hist[dst[i]], 1);
}

// block b sums hist[b*1024 .. b*1024+1023] -> csum[b]
__global__ __launch_bounds__(256) void chunk_sum_kernel(const int* __restrict__ hist,
                                                        int* __restrict__ csum, int N) {
    __shared__ int wpart[4];
    const int base = blockIdx.x * 1024 + threadIdx.x * 4;
    int s = 0;
    if (base + 3 < N) {
        int4 t = *(const int4*)(hist + base);
        s = t.x + t.y + t.z + t.w;
    } else {
#pragma unroll
        for (int j = 0; j < 4; ++j) if (base + j < N) s += hist[base + j];
    }
    s = wtotal64_i(s);
    if ((threadIdx.x & 63) == 0) wpart[threadIdx.x >> 6] = s;
    __syncthreads();
    if (threadIdx.x == 0) csum[blockIdx.x] = wpart[0] + wpart[1] + wpart[2] + wpart[3];
}

// single wave: exclusive scan of csum[0..nchunk) -> coff; rowptr[N] = total
__global__ void chunk_offsets_kernel(const int* __restrict__ csum, int* __restrict__ coff,
                                     int* __restrict__ rowptr, int nchunk, int N) {
    const int lane = threadIdx.x;
    int carry = 0;
    for (int base = 0; base < nchunk; base += 64) {
        const int i = base + lane;
        int val = (i < nchunk) ? csum[i] : 0;
        int incl = val;
#pragma unroll
        for (int off = 1; off < 64; off <<= 1) {
            int t = __shfl_up(incl, off, 64);
            if (lane >= off) incl += t;
        }
        if (i < nchunk) coff[i] = incl - val + carry;
        carry += __shfl(incl, 63, 64);
    }
    if (lane == 0) rowptr[N] = carry;
}

// block b: exclusive scan of its 1024 hist entries + coff[b] -> rowptr, cursor
// (rowptr may alias hist: each block reads its range into regs before writing)
__global__ __launch_bounds__(256) void chunk_apply_kernel(
        const int* __restrict__ hist, const int* __restrict__ coff,
        int* __restrict__ rowptr, int* __restrict__ cursor, int N) {
    __shared__ int wpart[4];
    const int wv = threadIdx.x >> 6;
    const int lane = threadIdx.x & 63;
    const int base = blockIdx.x * 1024 + threadIdx.x * 4;
    int v0 = 0, v1 = 0, v2 = 0, v3 = 0;
    if (base + 3 < N) {
        int4 t = *(const int4*)(hist + base);
        v0 = t.x; v1 = t.y; v2 = t.z; v3 = t.w;
    } else {
        if (base + 0 < N) v0 = hist[base + 0];
        if (base + 1 < N) v1 = hist[base + 1];
        if (base + 2 < N) v2 = hist[base + 2];
        if (base + 3 < N) v3 = hist[base + 3];
    }
    const int s = v0 + v1 + v2 + v3;
    int incl = s;
#pragma unroll
    for (int off = 1; off < 64; off <<= 1) {
        int t = __shfl_up(incl, off, 64);
        if (lane >= off) incl += t;
    }
    if (lane == 63) wpart[wv] = incl;
    __syncthreads();
    int excl = coff[blockIdx.x] + incl - s;
    for (int w = 0; w < wv; ++w) excl += wpart[w];
    if (base + 0 < N) { rowptr[base + 0] = excl; cursor[base + 0] = excl; excl += v0; }
    if (base + 1 < N) { rowptr[base + 1] = excl; cursor[base + 1] = excl; excl += v1; }
    if (base + 2 < N) { rowptr[base + 2] = excl; cursor[base + 2] = excl; excl += v2; }
    if (base + 3 < N) { rowptr[base + 3] = excl; cursor[base + 3] = excl; excl += v3; }
}

__global__ __launch_bounds__(256) void scatter_kernel(
        const int* __restrict__ dst, const int* __restrict__ src,
        const float* __restrict__ ef, int* __restrict__ cursor,
        int* __restrict__ srcp, float* __restrict__ efp, int E) {
    int i = blockIdx.x * blockDim.x + threadIdx.x;
    for (; i < E; i += gridDim.x * blockDim.x) {
        const int slot = atomicAdd(&cursor[dst[i]], 1);
        srcp[slot] = src[i];
        efp[slot]  = ef[i];
    }
}

// ---------------- node linear (f16 dot2) ----------------

__global__ __launch_bounds__(256, 4) void lin_kernel(
        const float* __restrict__ X, const float* __restrict__ W, int wstride,
        const float* __restrict__ b, float* __restrict__ Y, int N) {
    __shared__ __align__(16) _Float16 xbuf[4][EMB];
    const int wv = threadIdx.x >> 6;
    const int lane = threadIdx.x & 63;
    half2_t wh[32];
    load_w_f16(W, wstride, lane, wh);
    const float bias = b ? b[lane] : 0.0f;
    const int nW = gridDim.x * 4;
    for (int n = blockIdx.x * 4 + wv; n < N; n += nW) {
        xbuf[wv][lane] = (_Float16)X[(size_t)n * EMB + lane];
        Y[(size_t)n * EMB + lane] = matvec_f16(xbuf[wv], wh, bias);
    }
}

// ---------------- edge stage: CSR, wave per dst node ----------------

__global__ __launch_bounds__(256, 4) void edge_csr_kernel(
        const int* __restrict__ rowptr, const int* __restrict__ srcp,
        const float* __restrict__ efp,
        const float* __restrict__ RL, const float* __restrict__ LL,
        const float* __restrict__ Wecol, const float* __restrict__ g1,
        const float* __restrict__ b1,
        const float* __restrict__ Wf, const float* __restrict__ bfp,
        float* __restrict__ AGG, int Nr) {
    __shared__ __align__(16) _Float16 hbuf[4][EMB];
    const int wv = threadIdx.x >> 6;
    const int lane = threadIdx.x & 63;
    half2_t wh[32];
    load_w_f16(Wf, EMB, lane, wh);
    const float we  = Wecol[lane];
    const float g   = g1[lane];
    const float bb  = b1[lane];
    const float bf_ = bfp[lane];
    const int nW = gridDim.x * 4;
    for (int n = blockIdx.x * 4 + wv; n < Nr; n += nW) {
        const int beg = rowptr[n];
        const int end = rowptr[n + 1];
        const float rl = RL[(size_t)n * EMB + lane];
        float acc = 0.0f;
        if (beg < end) {
            float f  = efp[beg];
            float ll = LL[(size_t)srcp[beg] * EMB + lane];
            for (int idx = beg; idx < end; ++idx) {
                float f_n = 0.0f, ll_n = 0.0f;
                if (idx + 1 < end) {
                    f_n  = efp[idx + 1];
                    ll_n = LL[(size_t)srcp[idx + 1] * EMB + lane];
                }
                float h = rl + ll + f * we;
                const float s1 = wtotal64(h);
                const float s2 = wtotal64(h * h);
                const float m   = s1 * (1.0f / EMB);
                const float var = s2 * (1.0f / EMB) - m * m;
                float hn = fmaxf((h - m) * rsqrtf(var + EPSLN) * g + bb, 0.0f);
                hbuf[wv][lane] = (_Float16)hn;
                acc = matvec_f16(hbuf[wv], wh, acc);
                f = f_n; ll = ll_n;
            }
        }
        AGG[(size_t)n * EMB + lane] = acc + (float)(end - beg) * bf_;
    }
}

// ---------------- legacy atomic edge path (ws fallback) ----------------

__global__ __launch_bounds__(256, 4) void edge_kernel(
        const int* __restrict__ dst, const int* __restrict__ src,
        const float* __restrict__ ef,
        const float* __restrict__ RL, const float* __restrict__ LL,
        const float* __restrict__ Wecol, const float* __restrict__ g1,
        const float* __restrict__ b1,
        const float* __restrict__ Wf, const float* __restrict__ bfp,
        float* __restrict__ AGG) {
    __shared__ __align__(16) _Float16 hbuf[4][EMB];
    const int wv = threadIdx.x >> 6;
    const int lane = threadIdx.x & 63;
    half2_t wh[32];
    load_w_f16(Wf, EMB, lane, wh);
    const float we = Wecol[lane];
    const float g  = g1[lane];
    const float bb = b1[lane];
    const float bf_ = bfp[lane];
    const int nW = gridDim.x * 4;
    for (int e = blockIdx.x * 4 + wv; e < NEDGE; e += nW) {
        const int d = dst[e];
        const int s = src[e];
        const float f = ef[e];
        float h = RL[(size_t)d * EMB + lane] + LL[(size_t)s * EMB + lane] + f * we;
        const float s1 = wtotal64(h);
        const float s2 = wtotal64(h * h);
        const float m   = s1 * (1.0f / EMB);
        const float var = s2 * (1.0f / EMB) - m * m;
        float hn = fmaxf((h - m) * rsqrtf(var + EPSLN) * g + bb, 0.0f);
        hbuf[wv][lane] = (_Float16)hn;
        float acc = matvec_f16(hbuf[wv], wh, bf_);
        atomicAdd(&AGG[(size_t)d * EMB + lane], acc);
    }
}

// ---------------- output MLP ----------------

__global__ __launch_bounds__(256, 4) void out_kernel(
        const float* __restrict__ AGG, const float* __restrict__ RB,
        float* __restrict__ right,
        const float* __restrict__ g2, const float* __restrict__ b2,
        const float* __restrict__ Wo1, const float* __restrict__ Wo2,
        const float* __restrict__ bo2, int N) {
    __shared__ __align__(16) _Float16 zbuf[4][EMB];
    __shared__ __align__(16) _Float16 obuf[4][EMB];
    const int wv = threadIdx.x >> 6;
    const int lane = threadIdx.x & 63;
    half2_t wh1[32], wh2[32];
    load_w_f16(Wo1, 2 * EMB, lane, wh1);
    load_w_f16(Wo2, EMB, lane, wh2);
    const float g  = g2[lane];
    const float bb = b2[lane];
    const float bo = bo2[lane];
    const int nW = gridDim.x * 4;
    for (int n = blockIdx.x * 4 + wv; n < N; n += nW) {
        const float a = AGG[(size_t)n * EMB + lane];
        const float s1 = wtotal64(a);
        const float s2 = wtotal64(a * a);
        const float m   = s1 * (1.0f / EMB);
        const float var = s2 * (1.0f / EMB) - m * m;
        const float z = (a - m) * rsqrtf(var + EPSLN) * g + bb;
        zbuf[wv][lane] = (_Float16)z;
        float acc = matvec_f16(zbuf[wv], wh1, RB[(size_t)n * EMB + lane]);
        obuf[wv][lane] = (_Float16)fmaxf(acc, 0.0f);
        float acc2 = matvec_f16(obuf[wv], wh2, bo);
        right[(size_t)n * EMB + lane] += acc2;
    }
}

extern "C" void kernel_launch(void* const* d_in, const int* in_sizes, int n_in,
                              void* d_out, int out_size, void* d_ws, size_t ws_size,
                              hipStream_t stream) {
    const float* cf  = (const float*)d_in[0];
    const float* vfp = (const float*)d_in[1];
    const int*   ei  = (const int*)d_in[2];
    const float* ef  = (const float*)d_in[3];
    const float* Wl  = (const float*)d_in[4];
    const float* bl  = (const float*)d_in[5];
    const float* We  = (const float*)d_in[6];
    const float* Wr  = (const float*)d_in[7];
    const float* g1  = (const float*)d_in[8];
    const float* b1  = (const float*)d_in[9];
    const float* Wf  = (const float*)d_in[10];
    const float* bfp = (const float*)d_in[11];
    const float* g2  = (const float*)d_in[12];
    const float* b2  = (const float*)d_in[13];
    const float* Wo1 = (const float*)d_in[14];
    const float* bo1 = (const float*)d_in[15];
    const float* Wo2 = (const float*)d_in[16];
    const float* bo2 = (const float*)d_in[17];

    float* c = (float*)d_out;
    float* v = c + (size_t)NCON * EMB;
    (void)hipMemcpyAsync(c, cf,  (size_t)NCON * EMB * sizeof(float), hipMemcpyDeviceToDevice, stream);
    (void)hipMemcpyAsync(v, vfp, (size_t)NVAR * EMB * sizeof(float), hipMemcpyDeviceToDevice, stream);

    float* wsf = (float*)d_ws;
    size_t off = 0;
    float* AGG = wsf + off; off += (size_t)NVAR * EMB;   // 6.4M
    float* RL  = wsf + off; off += (size_t)NVAR * EMB;   // 6.4M (also RB)
    float* LL  = wsf + off; off += (size_t)NVAR * EMB;   // 6.4M
    int*   ptrC  = (int*)(wsf + off); off += 50004;      // hist then rowptr (aliased)
    int*   curC  = (int*)(wsf + off); off += 50004;
    int*   ptrV  = (int*)(wsf + off); off += 100004;
    int*   curV  = (int*)(wsf + off); off += 100004;
    int*   csumC = (int*)(wsf + off); off += 64;
    int*   coffC = (int*)(wsf + off); off += 64;
    int*   csumV = (int*)(wsf + off); off += 128;
    int*   coffV = (int*)(wsf + off); off += 128;
    int*   srcpC = (int*)(wsf + off); off += NEDGE;
    float* efpC  = wsf + off;         off += NEDGE;
    int*   srcpV = (int*)(wsf + off); off += NEDGE;
    float* efpV  = wsf + off;         off += NEDGE;
    const bool use_csr = ws_size >= off * sizeof(float);

    const int* ci = ei;
    const int* vi = ei + NEDGE;

    const dim3 blk(256);
    const int NB = 2048;
    const int nchC = (NCON + 1023) / 1024;   // 49
    const int nchV = (NVAR + 1023) / 1024;   // 98

    if (use_csr) {
        (void)hipMemsetAsync(ptrC, 0, NCON * sizeof(int), stream);
        (void)hipMemsetAsync(ptrV, 0, NVAR * sizeof(int), stream);
        hist_kernel<<<1024, blk, 0, stream>>>(ci, ptrC, NEDGE);
        hist_kernel<<<1024, blk, 0, stream>>>(vi, ptrV, NEDGE);
        chunk_sum_kernel<<<nchC, blk, 0, stream>>>(ptrC, csumC, NCON);
        chunk_sum_kernel<<<nchV, blk, 0, stream>>>(ptrV, csumV, NVAR);
        chunk_offsets_kernel<<<1, 64, 0, stream>>>(csumC, coffC, ptrC, nchC, NCON);
        chunk_offsets_kernel<<<1, 64, 0, stream>>>(csumV, coffV, ptrV, nchV, NVAR);
        chunk_apply_kernel<<<nchC, blk, 0, stream>>>(ptrC, coffC, ptrC, curC, NCON);
        chunk_apply_kernel<<<nchV, blk, 0, stream>>>(ptrV, coffV, ptrV, curV, NVAR);
        scatter_kernel<<<1024, blk, 0, stream>>>(ci, vi, ef, curC, srcpC, efpC, NEDGE);
        scatter_kernel<<<1024, blk, 0, stream>>>(vi, ci, ef, curV, srcpV, efpV, NEDGE);
    }

    for (int k = 0; k < 4; ++k) {
        const bool v2c = ((k & 1) == 0);
        float* right   = v2c ? c : v;
        float* left    = v2c ? v : c;
        const int Nr   = v2c ? NCON : NVAR;
        const int Nl   = v2c ? NVAR : NCON;
        const int* dst = v2c ? ci : vi;
        const int* src = v2c ? vi : ci;

        lin_kernel<<<NB, blk, 0, stream>>>(right, Wl + (size_t)k * EMB * EMB, EMB,
                                           bl + (size_t)k * EMB, RL, Nr);
        lin_kernel<<<NB, blk, 0, stream>>>(left,  Wr + (size_t)k * EMB * EMB, EMB,
                                           nullptr, LL, Nl);
        if (use_csr) {
            edge_csr_kernel<<<NB, blk, 0, stream>>>(
                v2c ? ptrC : ptrV, v2c ? srcpC : srcpV, v2c ? efpC : efpV,
                RL, LL, We + (size_t)k * EMB,
                g1 + (size_t)k * EMB, b1 + (size_t)k * EMB,
                Wf + (size_t)k * EMB * EMB, bfp + (size_t)k * EMB, AGG, Nr);
        } else {
            (void)hipMemsetAsync(AGG, 0, (size_t)Nr * EMB * sizeof(float), stream);
            edge_kernel<<<NB, blk, 0, stream>>>(dst, src, ef, RL, LL,
                                                We + (size_t)k * EMB,
                                                g1 + (size_t)k * EMB, b1 + (size_t)k * EMB,
                                                Wf + (size_t)k * EMB * EMB,
                                                bfp + (size_t)k * EMB, AGG);
        }
        lin_kernel<<<NB, blk, 0, stream>>>(right, Wo1 + (size_t)k * EMB * 2 * EMB + EMB,
                                           2 * EMB, bo1 + (size_t)k * EMB, RL, Nr);
        out_kernel<<<NB, blk, 0, stream>>>(AGG, RL, right,
                                           g2 + (size_t)k * EMB, b2 + (size_t)k * EMB,
                                           Wo1 + (size_t)k * EMB * 2 * EMB,
                                           Wo2 + (size_t)k * EMB * EMB,
                                           bo2 + (size_t)k * EMB, Nr);
    }
}

// Round 5
// 1594.495 us; speedup vs baseline: 2.8686x; 1.5365x over previous
//
#include <hip/hip_runtime.h>

#define EMB   64
#define NCON  50000
#define NVAR  100000
#define NEDGE 1600000
#define EPSLN 1e-5f

// padded-CSR capacities (worst case: every node pads +15)
#define PADEC (NEDGE + 15 * NCON)    // 2,350,000
#define PADEV (NEDGE + 15 * NVAR)    // 3,100,000
#define GCAPC (PADEC / 16)           // 146,875
#define GCAPV (PADEV / 16)           // 193,750

typedef _Float16 half2_t __attribute__((ext_vector_type(2)));
typedef _Float16 f16x8  __attribute__((ext_vector_type(8)));
typedef float    f32x4  __attribute__((ext_vector_type(4)));

// ---- wave-total via DPP (no DS ops) ----
template <int CTRL, int RMASK>
__device__ __forceinline__ float dpp_add_f(float x) {
    int m = __builtin_amdgcn_update_dpp(0, __builtin_bit_cast(int, x), CTRL, RMASK, 0xf, true);
    return x + __builtin_bit_cast(float, m);
}
__device__ __forceinline__ float wtotal64(float x) {
    x = dpp_add_f<0x111, 0xf>(x);
    x = dpp_add_f<0x112, 0xf>(x);
    x = dpp_add_f<0x114, 0xf>(x);
    x = dpp_add_f<0x118, 0xf>(x);
    x = dpp_add_f<0x142, 0xa>(x);
    x = dpp_add_f<0x143, 0xc>(x);
    return __builtin_bit_cast(float, __builtin_amdgcn_readlane(__builtin_bit_cast(int, x), 63));
}
template <int CTRL, int RMASK>
__device__ __forceinline__ int dpp_add_i(int x) {
    return x + __builtin_amdgcn_update_dpp(0, x, CTRL, RMASK, 0xf, true);
}
__device__ __forceinline__ int wtotal64_i(int x) {
    x = dpp_add_i<0x111, 0xf>(x);
    x = dpp_add_i<0x112, 0xf>(x);
    x = dpp_add_i<0x114, 0xf>(x);
    x = dpp_add_i<0x118, 0xf>(x);
    x = dpp_add_i<0x142, 0xa>(x);
    x = dpp_add_i<0x143, 0xc>(x);
    return __builtin_amdgcn_readlane(x, 63);
}

__device__ __forceinline__ float dot2f(half2_t a, half2_t b, float c) {
    return __builtin_amdgcn_fdot2(a, b, c, false);
}

// 8 x ds_read_b128 + 32 x v_dot2 with 4 independent accumulator chains
__device__ __forceinline__ float matvec_f16(const _Float16* __restrict__ buf,
                                            const half2_t* __restrict__ wh, float acc) {
    const float4* hp4 = (const float4*)buf;
    float a0 = acc, a1 = 0.0f, a2 = 0.0f, a3 = 0.0f;
#pragma unroll
    for (int j4 = 0; j4 < 8; ++j4) {
        float4 t = hp4[j4];
        a0 = dot2f(wh[4 * j4 + 0], __builtin_bit_cast(half2_t, t.x), a0);
        a1 = dot2f(wh[4 * j4 + 1], __builtin_bit_cast(half2_t, t.y), a1);
        a2 = dot2f(wh[4 * j4 + 2], __builtin_bit_cast(half2_t, t.z), a2);
        a3 = dot2f(wh[4 * j4 + 3], __builtin_bit_cast(half2_t, t.w), a3);
    }
    return (a0 + a1) + (a2 + a3);
}

__device__ __forceinline__ void load_w_f16(const float* __restrict__ W, int stride,
                                           int lane, half2_t* wh) {
#pragma unroll
    for (int j4 = 0; j4 < 16; ++j4) {
        float4 t = *(const float4*)(W + (size_t)lane * stride + j4 * 4);
        wh[2 * j4 + 0] = half2_t{(_Float16)t.x, (_Float16)t.y};
        wh[2 * j4 + 1] = half2_t{(_Float16)t.z, (_Float16)t.w};
    }
}

// ---------------- CSR build ----------------

__global__ __launch_bounds__(256) void hist_kernel(const int* __restrict__ dst,
                                                   int* __restrict__ hist, int E) {
    int i = blockIdx.x * blockDim.x + threadIdx.x;
    for (; i < E; i += gridDim.x * blockDim.x)
        atomicAdd(&hist[dst[i]], 1);
}

template <bool PAD>
__global__ __launch_bounds__(256) void chunk_sum_kernel(const int* __restrict__ hist,
                                                        int* __restrict__ csum, int N) {
    __shared__ int wpart[4];
    const int base = blockIdx.x * 1024 + threadIdx.x * 4;
    int s = 0;
    if (base + 3 < N) {
        int4 t = *(const int4*)(hist + base);
        if (PAD) s = ((t.x+15)&~15) + ((t.y+15)&~15) + ((t.z+15)&~15) + ((t.w+15)&~15);
        else     s = t.x + t.y + t.z + t.w;
    } else {
#pragma unroll
        for (int j = 0; j < 4; ++j)
            if (base + j < N) { int v = hist[base + j]; s += PAD ? ((v+15)&~15) : v; }
    }
    s = wtotal64_i(s);
    if ((threadIdx.x & 63) == 0) wpart[threadIdx.x >> 6] = s;
    __syncthreads();
    if (threadIdx.x == 0) csum[blockIdx.x] = wpart[0] + wpart[1] + wpart[2] + wpart[3];
}

__global__ void chunk_offsets_kernel(const int* __restrict__ csum, int* __restrict__ coff,
                                     int* __restrict__ rowptr, int nchunk, int N) {
    const int lane = threadIdx.x;
    int carry = 0;
    for (int base = 0; base < nchunk; base += 64) {
        const int i = base + lane;
        int val = (i < nchunk) ? csum[i] : 0;
        int incl = val;
#pragma unroll
        for (int off = 1; off < 64; off <<= 1) {
            int t = __shfl_up(incl, off, 64);
            if (lane >= off) incl += t;
        }
        if (i < nchunk) coff[i] = incl - val + carry;
        carry += __shfl(incl, 63, 64);
    }
    if (lane == 0) rowptr[N] = carry;
}

template <bool PAD>
__global__ __launch_bounds__(256) void chunk_apply_kernel(
        const int* __restrict__ hist, const int* __restrict__ coff,
        int* __restrict__ rowptr, int* __restrict__ cursor, int N) {
    __shared__ int wpart[4];
    const int wv = threadIdx.x >> 6;
    const int lane = threadIdx.x & 63;
    const int base = blockIdx.x * 1024 + threadIdx.x * 4;
    int v0 = 0, v1 = 0, v2 = 0, v3 = 0;
    if (base + 3 < N) {
        int4 t = *(const int4*)(hist + base);
        v0 = t.x; v1 = t.y; v2 = t.z; v3 = t.w;
    } else {
        if (base + 0 < N) v0 = hist[base + 0];
        if (base + 1 < N) v1 = hist[base + 1];
        if (base + 2 < N) v2 = hist[base + 2];
        if (base + 3 < N) v3 = hist[base + 3];
    }
    if (PAD) { v0 = (v0+15)&~15; v1 = (v1+15)&~15; v2 = (v2+15)&~15; v3 = (v3+15)&~15; }
    const int s = v0 + v1 + v2 + v3;
    int incl = s;
#pragma unroll
    for (int off = 1; off < 64; off <<= 1) {
        int t = __shfl_up(incl, off, 64);
        if (lane >= off) incl += t;
    }
    if (lane == 63) wpart[wv] = incl;
    __syncthreads();
    int excl = coff[blockIdx.x] + incl - s;
    for (int w = 0; w < wv; ++w) excl += wpart[w];
    if (base + 0 < N) { rowptr[base + 0] = excl; cursor[base + 0] = excl; excl += v0; }
    if (base + 1 < N) { rowptr[base + 1] = excl; cursor[base + 1] = excl; excl += v1; }
    if (base + 2 < N) { rowptr[base + 2] = excl; cursor[base + 2] = excl; excl += v2; }
    if (base + 3 < N) { rowptr[base + 3] = excl; cursor[base + 3] = excl; excl += v3; }
}

__global__ __launch_bounds__(256) void scatter_kernel(
        const int* __restrict__ dst, const int* __restrict__ src,
        const float* __restrict__ ef, int* __restrict__ cursor,
        int* __restrict__ srcp, float* __restrict__ efp, int E) {
    int i = blockIdx.x * blockDim.x + threadIdx.x;
    for (; i < E; i += gridDim.x * blockDim.x) {
        const int slot = atomicAdd(&cursor[dst[i]], 1);
        srcp[slot] = src[i];
        efp[slot]  = ef[i];
    }
}

// group -> node map (each node's padded range is a whole number of 16-edge groups)
__global__ __launch_bounds__(256) void g2n_kernel(const int* __restrict__ rp16,
                                                  int* __restrict__ g2n, int N) {
    int n = blockIdx.x * blockDim.x + threadIdx.x;
    for (; n < N; n += gridDim.x * blockDim.x) {
        const int g0 = rp16[n] >> 4, g1v = rp16[n + 1] >> 4;
        for (int g = g0; g < g1v; ++g) g2n[g] = n;
    }
}

// ---------------- node linear (f16 dot2) ----------------

__global__ __launch_bounds__(256, 4) void lin_kernel(
        const float* __restrict__ X, const float* __restrict__ W, int wstride,
        const float* __restrict__ b, float* __restrict__ Y, int N) {
    __shared__ __align__(16) _Float16 xbuf[4][EMB];
    const int wv = threadIdx.x >> 6;
    const int lane = threadIdx.x & 63;
    half2_t wh[32];
    load_w_f16(W, wstride, lane, wh);
    const float bias = b ? b[lane] : 0.0f;
    const int nW = gridDim.x * 4;
    for (int n = blockIdx.x * 4 + wv; n < N; n += nW) {
        xbuf[wv][lane] = (_Float16)X[(size_t)n * EMB + lane];
        Y[(size_t)n * EMB + lane] = matvec_f16(xbuf[wv], wh, bias);
    }
}

// ---------------- edge stage: padded CSR, 16 edges per wave, MFMA ----------------
// A-frag: A[m = lane&15][k = (lane>>4)*8 + j]  (j=0..7; frag1 at k+32)
// B-frag: B[n = lane&15][k = (lane>>4)*8 + j]  = Wf[n][k]  (h @ Wf^T)
// C-frag: D[m = (lane>>4)*4 + reg][n = lane&15]  per 16-wide N-tile

__global__ __launch_bounds__(256, 3) void edge_mfma_kernel(
        const int* __restrict__ g2n, const int* __restrict__ rp16,
        const int* __restrict__ deg, const int* __restrict__ ngp,
        const int* __restrict__ srcp, const float* __restrict__ efp,
        const float* __restrict__ RL, const float* __restrict__ LL,
        const float* __restrict__ We, const float* __restrict__ g1,
        const float* __restrict__ b1, const float* __restrict__ Wf,
        float* __restrict__ AGG) {
    const int lane = threadIdx.x & 63;
    const int col  = lane & 15;       // m for A, n for B/C
    const int quad = lane >> 4;
    const int kb   = quad * 8;        // k-slice base (frag0; +32 for frag1)

    // per-lane k-slice constants
    float we[16], gk[16], bk[16];
#pragma unroll
    for (int j = 0; j < 8; ++j) {
        we[j] = We[kb + j];       we[8 + j] = We[kb + 32 + j];
        gk[j] = g1[kb + j];       gk[8 + j] = g1[kb + 32 + j];
        bk[j] = b1[kb + j];       bk[8 + j] = b1[kb + 32 + j];
    }
    // B fragments: 4 N-tiles x 2 K-frags
    f16x8 B0[4], B1[4];
#pragma unroll
    for (int t = 0; t < 4; ++t) {
        const float* wrow = Wf + (size_t)(t * 16 + col) * EMB;
#pragma unroll
        for (int j = 0; j < 8; ++j) {
            B0[t][j] = (_Float16)wrow[kb + j];
            B1[t][j] = (_Float16)wrow[kb + 32 + j];
        }
    }

    const int ngroups = ngp[0] >> 4;
    const int nW = gridDim.x * 4;
    for (int g = blockIdx.x * 4 + (threadIdx.x >> 6); g < ngroups; g += nW) {
        const int n  = g2n[g];
        const int gi = g - (rp16[n] >> 4);
        const int cnt = deg[n] - gi * 16;         // #real edges in this group (1..16)
        const int e = (g << 4) + col;             // this lane's edge slot (m = col)
        const int s = srcp[e];
        const float f = efp[e];
        const float* llrow = LL + (size_t)s * EMB;
        const float* rlrow = RL + (size_t)n * EMB;

        float ll16[16], rl16[16], h[16];
        *(float4*)&ll16[0]  = *(const float4*)(llrow + kb);
        *(float4*)&ll16[4]  = *(const float4*)(llrow + kb + 4);
        *(float4*)&ll16[8]  = *(const float4*)(llrow + kb + 32);
        *(float4*)&ll16[12] = *(const float4*)(llrow + kb + 36);
        *(float4*)&rl16[0]  = *(const float4*)(rlrow + kb);
        *(float4*)&rl16[4]  = *(const float4*)(rlrow + kb + 4);
        *(float4*)&rl16[8]  = *(const float4*)(rlrow + kb + 32);
        *(float4*)&rl16[12] = *(const float4*)(rlrow + kb + 36);

        float ps = 0.0f, pq = 0.0f;
#pragma unroll
        for (int j = 0; j < 16; ++j) {
            h[j] = rl16[j] + ll16[j] + f * we[j];
            ps += h[j];
            pq += h[j] * h[j];
        }
        // row reduce across the 4 lanes holding this edge (lane ^ 16, lane ^ 32)
        ps += __shfl_xor(ps, 16, 64); ps += __shfl_xor(ps, 32, 64);
        pq += __shfl_xor(pq, 16, 64); pq += __shfl_xor(pq, 32, 64);
        const float mean = ps * (1.0f / EMB);
        const float var  = pq * (1.0f / EMB) - mean * mean;
        const float rs   = rsqrtf(var + EPSLN);
        const bool live  = col < cnt;

        f16x8 A0, A1;
#pragma unroll
        for (int j = 0; j < 8; ++j) {
            float h0 = fmaxf((h[j]     - mean) * rs * gk[j]     + bk[j],     0.0f);
            float h1 = fmaxf((h[8 + j] - mean) * rs * gk[8 + j] + bk[8 + j], 0.0f);
            A0[j] = live ? (_Float16)h0 : (_Float16)0.0f;
            A1[j] = live ? (_Float16)h1 : (_Float16)0.0f;
        }

        f32x4 c0 = {0,0,0,0}, c1 = {0,0,0,0}, c2 = {0,0,0,0}, c3 = {0,0,0,0};
        c0 = __builtin_amdgcn_mfma_f32_16x16x32_f16(A0, B0[0], c0, 0, 0, 0);
        c0 = __builtin_amdgcn_mfma_f32_16x16x32_f16(A1, B1[0], c0, 0, 0, 0);
        c1 = __builtin_amdgcn_mfma_f32_16x16x32_f16(A0, B0[1], c1, 0, 0, 0);
        c1 = __builtin_amdgcn_mfma_f32_16x16x32_f16(A1, B1[1], c1, 0, 0, 0);
        c2 = __builtin_amdgcn_mfma_f32_16x16x32_f16(A0, B0[2], c2, 0, 0, 0);
        c2 = __builtin_amdgcn_mfma_f32_16x16x32_f16(A1, B1[2], c2, 0, 0, 0);
        c3 = __builtin_amdgcn_mfma_f32_16x16x32_f16(A0, B0[3], c3, 0, 0, 0);
        c3 = __builtin_amdgcn_mfma_f32_16x16x32_f16(A1, B1[3], c3, 0, 0, 0);

        // all 16 rows belong to node n: reduce over regs then across quads
        float s0 = (c0[0] + c0[1]) + (c0[2] + c0[3]);
        float s1 = (c1[0] + c1[1]) + (c1[2] + c1[3]);
        float s2 = (c2[0] + c2[1]) + (c2[2] + c2[3]);
        float s3 = (c3[0] + c3[1]) + (c3[2] + c3[3]);
        s0 += __shfl_xor(s0, 16, 64); s0 += __shfl_xor(s0, 32, 64);
        s1 += __shfl_xor(s1, 16, 64); s1 += __shfl_xor(s1, 32, 64);
        s2 += __shfl_xor(s2, 16, 64); s2 += __shfl_xor(s2, 32, 64);
        s3 += __shfl_xor(s3, 16, 64); s3 += __shfl_xor(s3, 32, 64);
        const float outv = (quad == 0) ? s0 : (quad == 1) ? s1 : (quad == 2) ? s2 : s3;
        atomicAdd(&AGG[(size_t)n * EMB + quad * 16 + col], outv);
    }
}

// ---------------- fallback edge path (wave per node, dot2) ----------------

__global__ __launch_bounds__(256, 4) void edge_csr_kernel(
        const int* __restrict__ rowptr, const int* __restrict__ srcp,
        const float* __restrict__ efp,
        const float* __restrict__ RL, const float* __restrict__ LL,
        const float* __restrict__ Wecol, const float* __restrict__ g1,
        const float* __restrict__ b1,
        const float* __restrict__ Wf, const float* __restrict__ bfp,
        float* __restrict__ AGG, int Nr) {
    __shared__ __align__(16) _Float16 hbuf[4][EMB];
    const int wv = threadIdx.x >> 6;
    const int lane = threadIdx.x & 63;
    half2_t wh[32];
    load_w_f16(Wf, EMB, lane, wh);
    const float we  = Wecol[lane];
    const float g   = g1[lane];
    const float bb  = b1[lane];
    const float bf_ = bfp[lane];
    const int nW = gridDim.x * 4;
    for (int n = blockIdx.x * 4 + wv; n < Nr; n += nW) {
        const int beg = rowptr[n];
        const int end = rowptr[n + 1];
        const float rl = RL[(size_t)n * EMB + lane];
        float acc = 0.0f;
        if (beg < end) {
            float f  = efp[beg];
            float ll = LL[(size_t)srcp[beg] * EMB + lane];
            for (int idx = beg; idx < end; ++idx) {
                float f_n = 0.0f, ll_n = 0.0f;
                if (idx + 1 < end) {
                    f_n  = efp[idx + 1];
                    ll_n = LL[(size_t)srcp[idx + 1] * EMB + lane];
                }
                float h = rl + ll + f * we;
                const float s1 = wtotal64(h);
                const float s2 = wtotal64(h * h);
                const float m   = s1 * (1.0f / EMB);
                const float var = s2 * (1.0f / EMB) - m * m;
                float hn = fmaxf((h - m) * rsqrtf(var + EPSLN) * g + bb, 0.0f);
                hbuf[wv][lane] = (_Float16)hn;
                acc = matvec_f16(hbuf[wv], wh, acc);
                f = f_n; ll = ll_n;
            }
        }
        AGG[(size_t)n * EMB + lane] = acc + (float)(end - beg) * bf_;
    }
}

// ---------------- output MLP ----------------

__global__ __launch_bounds__(256, 4) void out_kernel(
        const float* __restrict__ AGG, const float* __restrict__ RB,
        float* __restrict__ right,
        const float* __restrict__ g2, const float* __restrict__ b2,
        const float* __restrict__ Wo1, const float* __restrict__ Wo2,
        const float* __restrict__ bo2,
        const int* __restrict__ deg, const float* __restrict__ bfp, int N) {
    __shared__ __align__(16) _Float16 zbuf[4][EMB];
    __shared__ __align__(16) _Float16 obuf[4][EMB];
    const int wv = threadIdx.x >> 6;
    const int lane = threadIdx.x & 63;
    half2_t wh1[32], wh2[32];
    load_w_f16(Wo1, 2 * EMB, lane, wh1);
    load_w_f16(Wo2, EMB, lane, wh2);
    const float g  = g2[lane];
    const float bb = b2[lane];
    const float bo = bo2[lane];
    const float bfv = deg ? bfp[lane] : 0.0f;
    const int nW = gridDim.x * 4;
    for (int n = blockIdx.x * 4 + wv; n < N; n += nW) {
        float a = AGG[(size_t)n * EMB + lane];
        if (deg) a += (float)deg[n] * bfv;   // per-edge bias folded: deg * bf
        const float s1 = wtotal64(a);
        const float s2 = wtotal64(a * a);
        const float m   = s1 * (1.0f / EMB);
        const float var = s2 * (1.0f / EMB) - m * m;
        const float z = (a - m) * rsqrtf(var + EPSLN) * g + bb;
        zbuf[wv][lane] = (_Float16)z;
        float acc = matvec_f16(zbuf[wv], wh1, RB[(size_t)n * EMB + lane]);
        obuf[wv][lane] = (_Float16)fmaxf(acc, 0.0f);
        float acc2 = matvec_f16(obuf[wv], wh2, bo);
        right[(size_t)n * EMB + lane] += acc2;
    }
}

extern "C" void kernel_launch(void* const* d_in, const int* in_sizes, int n_in,
                              void* d_out, int out_size, void* d_ws, size_t ws_size,
                              hipStream_t stream) {
    const float* cf  = (const float*)d_in[0];
    const float* vfp = (const float*)d_in[1];
    const int*   ei  = (const int*)d_in[2];
    const float* ef  = (const float*)d_in[3];
    const float* Wl  = (const float*)d_in[4];
    const float* bl  = (const float*)d_in[5];
    const float* We  = (const float*)d_in[6];
    const float* Wr  = (const float*)d_in[7];
    const float* g1  = (const float*)d_in[8];
    const float* b1  = (const float*)d_in[9];
    const float* Wf  = (const float*)d_in[10];
    const float* bfp = (const float*)d_in[11];
    const float* g2  = (const float*)d_in[12];
    const float* b2  = (const float*)d_in[13];
    const float* Wo1 = (const float*)d_in[14];
    const float* bo1 = (const float*)d_in[15];
    const float* Wo2 = (const float*)d_in[16];
    const float* bo2 = (const float*)d_in[17];

    float* c = (float*)d_out;
    float* v = c + (size_t)NCON * EMB;
    (void)hipMemcpyAsync(c, cf,  (size_t)NCON * EMB * sizeof(float), hipMemcpyDeviceToDevice, stream);
    (void)hipMemcpyAsync(v, vfp, (size_t)NVAR * EMB * sizeof(float), hipMemcpyDeviceToDevice, stream);

    float* wsf = (float*)d_ws;
    size_t off = 0;
    float* AGG = wsf + off; off += (size_t)NVAR * EMB;
    float* RL  = wsf + off; off += (size_t)NVAR * EMB;
    float* LL  = wsf + off; off += (size_t)NVAR * EMB;
    int* degC  = (int*)(wsf + off); off += NCON;
    int* degV  = (int*)(wsf + off); off += NVAR;
    int* rp16C = (int*)(wsf + off); off += NCON + 4;
    int* curC  = (int*)(wsf + off); off += NCON;
    int* rp16V = (int*)(wsf + off); off += NVAR + 4;
    int* curV  = (int*)(wsf + off); off += NVAR;
    int* csumC = (int*)(wsf + off); off += 128;
    int* coffC = (int*)(wsf + off); off += 128;
    int* csumV = (int*)(wsf + off); off += 128;
    int* coffV = (int*)(wsf + off); off += 128;
    int* g2nC  = (int*)(wsf + off); off += GCAPC;
    int* g2nV  = (int*)(wsf + off); off += GCAPV;
    size_t off_mfma_edges = off;
    // MFMA layout: padded edge arrays
    int*   srcpC = (int*)(wsf + off); off += PADEC;
    float* efpC  = wsf + off;         off += PADEC;
    int*   srcpV = (int*)(wsf + off); off += PADEV;
    float* efpV  = wsf + off;         off += PADEV;
    const bool use_mfma = ws_size >= off * sizeof(float);
    if (!use_mfma) {
        // fallback layout: unpadded edge arrays (overlaps g2n region unused sizes are fine)
        off = off_mfma_edges;
        srcpC = (int*)(wsf + off); off += NEDGE;
        efpC  = wsf + off;         off += NEDGE;
        srcpV = (int*)(wsf + off); off += NEDGE;
        efpV  = wsf + off;         off += NEDGE;
    }
    const bool use_csr = ws_size >= off * sizeof(float);

    const int* ci = ei;
    const int* vi = ei + NEDGE;

    const dim3 blk(256);
    const int NB = 2048;
    const int nchC = (NCON + 1023) / 1024;   // 49
    const int nchV = (NVAR + 1023) / 1024;   // 98

    if (use_csr) {
        (void)hipMemsetAsync(degC, 0, NCON * sizeof(int), stream);
        (void)hipMemsetAsync(degV, 0, NVAR * sizeof(int), stream);
        hist_kernel<<<1024, blk, 0, stream>>>(ci, degC, NEDGE);
        hist_kernel<<<1024, blk, 0, stream>>>(vi, degV, NEDGE);
        if (use_mfma) {
            chunk_sum_kernel<true><<<nchC, blk, 0, stream>>>(degC, csumC, NCON);
            chunk_sum_kernel<true><<<nchV, blk, 0, stream>>>(degV, csumV, NVAR);
            chunk_offsets_kernel<<<1, 64, 0, stream>>>(csumC, coffC, rp16C, nchC, NCON);
            chunk_offsets_kernel<<<1, 64, 0, stream>>>(csumV, coffV, rp16V, nchV, NVAR);
            chunk_apply_kernel<true><<<nchC, blk, 0, stream>>>(degC, coffC, rp16C, curC, NCON);
            chunk_apply_kernel<true><<<nchV, blk, 0, stream>>>(degV, coffV, rp16V, curV, NVAR);
            g2n_kernel<<<256, blk, 0, stream>>>(rp16C, g2nC, NCON);
            g2n_kernel<<<256, blk, 0, stream>>>(rp16V, g2nV, NVAR);
            (void)hipMemsetAsync(srcpC, 0, (size_t)PADEC * sizeof(int), stream);
            (void)hipMemsetAsync(srcpV, 0, (size_t)PADEV * sizeof(int), stream);
        } else {
            chunk_sum_kernel<false><<<nchC, blk, 0, stream>>>(degC, csumC, NCON);
            chunk_sum_kernel<false><<<nchV, blk, 0, stream>>>(degV, csumV, NVAR);
            chunk_offsets_kernel<<<1, 64, 0, stream>>>(csumC, coffC, rp16C, nchC, NCON);
            chunk_offsets_kernel<<<1, 64, 0, stream>>>(csumV, coffV, rp16V, nchV, NVAR);
            chunk_apply_kernel<false><<<nchC, blk, 0, stream>>>(degC, coffC, rp16C, curC, NCON);
            chunk_apply_kernel<false><<<nchV, blk, 0, stream>>>(degV, coffV, rp16V, curV, NVAR);
        }
        scatter_kernel<<<1024, blk, 0, stream>>>(ci, vi, ef, curC, srcpC, efpC, NEDGE);
        scatter_kernel<<<1024, blk, 0, stream>>>(vi, ci, ef, curV, srcpV, efpV, NEDGE);
    }

    for (int k = 0; k < 4; ++k) {
        const bool v2c = ((k & 1) == 0);
        float* right   = v2c ? c : v;
        float* left    = v2c ? v : c;
        const int Nr   = v2c ? NCON : NVAR;
        const int Nl   = v2c ? NVAR : NCON;

        lin_kernel<<<NB, blk, 0, stream>>>(right, Wl + (size_t)k * EMB * EMB, EMB,
                                           bl + (size_t)k * EMB, RL, Nr);
        lin_kernel<<<NB, blk, 0, stream>>>(left,  Wr + (size_t)k * EMB * EMB, EMB,
                                           nullptr, LL, Nl);
        const int* degp = v2c ? degC : degV;
        if (use_mfma) {
            (void)hipMemsetAsync(AGG, 0, (size_t)Nr * EMB * sizeof(float), stream);
            edge_mfma_kernel<<<NB, blk, 0, stream>>>(
                v2c ? g2nC : g2nV, v2c ? rp16C : rp16V, degp,
                (v2c ? rp16C : rp16V) + Nr,
                v2c ? srcpC : srcpV, v2c ? efpC : efpV,
                RL, LL, We + (size_t)k * EMB,
                g1 + (size_t)k * EMB, b1 + (size_t)k * EMB,
                Wf + (size_t)k * EMB * EMB, AGG);
        } else {
            edge_csr_kernel<<<NB, blk, 0, stream>>>(
                v2c ? rp16C : rp16V, v2c ? srcpC : srcpV, v2c ? efpC : efpV,
                RL, LL, We + (size_t)k * EMB,
                g1 + (size_t)k * EMB, b1 + (size_t)k * EMB,
                Wf + (size_t)k * EMB * EMB, bfp + (size_t)k * EMB, AGG, Nr);
        }
        lin_kernel<<<NB, blk, 0, stream>>>(right, Wo1 + (size_t)k * EMB * 2 * EMB + EMB,
                                           2 * EMB, bo1 + (size_t)k * EMB, RL, Nr);
        out_kernel<<<NB, blk, 0, stream>>>(AGG, RL, right,
                                           g2 + (size_t)k * EMB, b2 + (size_t)k * EMB,
                                           Wo1 + (size_t)k * EMB * 2 * EMB,
                                           Wo2 + (size_t)k * EMB * EMB,
                                           bo2 + (size_t)k * EMB,
                                           use_mfma ? degp : nullptr,
                                           bfp + (size_t)k * EMB, Nr);
    }
}

// Round 6
// 1524.136 us; speedup vs baseline: 3.0010x; 1.0462x over previous
//
#include <hip/hip_runtime.h>

#define EMB   64
#define NCON  50000
#define NVAR  100000
#define NEDGE 1600000
#define EPSLN 1e-5f

// padded-CSR capacities (worst case: every node pads +15)
#define PADEC (NEDGE + 15 * NCON)    // 2,350,000
#define PADEV (NEDGE + 15 * NVAR)    // 3,100,000

typedef _Float16 half2_t __attribute__((ext_vector_type(2)));
typedef _Float16 f16x8  __attribute__((ext_vector_type(8)));
typedef float    f32x4  __attribute__((ext_vector_type(4)));

// ---- wave-total via DPP (no DS ops) ----
template <int CTRL, int RMASK>
__device__ __forceinline__ float dpp_add_f(float x) {
    int m = __builtin_amdgcn_update_dpp(0, __builtin_bit_cast(int, x), CTRL, RMASK, 0xf, true);
    return x + __builtin_bit_cast(float, m);
}
__device__ __forceinline__ float wtotal64(float x) {
    x = dpp_add_f<0x111, 0xf>(x);
    x = dpp_add_f<0x112, 0xf>(x);
    x = dpp_add_f<0x114, 0xf>(x);
    x = dpp_add_f<0x118, 0xf>(x);
    x = dpp_add_f<0x142, 0xa>(x);
    x = dpp_add_f<0x143, 0xc>(x);
    return __builtin_bit_cast(float, __builtin_amdgcn_readlane(__builtin_bit_cast(int, x), 63));
}
template <int CTRL, int RMASK>
__device__ __forceinline__ int dpp_add_i(int x) {
    return x + __builtin_amdgcn_update_dpp(0, x, CTRL, RMASK, 0xf, true);
}
__device__ __forceinline__ int wtotal64_i(int x) {
    x = dpp_add_i<0x111, 0xf>(x);
    x = dpp_add_i<0x112, 0xf>(x);
    x = dpp_add_i<0x114, 0xf>(x);
    x = dpp_add_i<0x118, 0xf>(x);
    x = dpp_add_i<0x142, 0xa>(x);
    x = dpp_add_i<0x143, 0xc>(x);
    return __builtin_amdgcn_readlane(x, 63);
}

__device__ __forceinline__ float dot2f(half2_t a, half2_t b, float c) {
    return __builtin_amdgcn_fdot2(a, b, c, false);
}

// 8 x ds_read_b128 + 32 x v_dot2 with 4 independent accumulator chains
__device__ __forceinline__ float matvec_f16(const _Float16* __restrict__ buf,
                                            const half2_t* __restrict__ wh, float acc) {
    const float4* hp4 = (const float4*)buf;
    float a0 = acc, a1 = 0.0f, a2 = 0.0f, a3 = 0.0f;
#pragma unroll
    for (int j4 = 0; j4 < 8; ++j4) {
        float4 t = hp4[j4];
        a0 = dot2f(wh[4 * j4 + 0], __builtin_bit_cast(half2_t, t.x), a0);
        a1 = dot2f(wh[4 * j4 + 1], __builtin_bit_cast(half2_t, t.y), a1);
        a2 = dot2f(wh[4 * j4 + 2], __builtin_bit_cast(half2_t, t.z), a2);
        a3 = dot2f(wh[4 * j4 + 3], __builtin_bit_cast(half2_t, t.w), a3);
    }
    return (a0 + a1) + (a2 + a3);
}

__device__ __forceinline__ void load_w_f16(const float* __restrict__ W, int stride,
                                           int lane, half2_t* wh) {
#pragma unroll
    for (int j4 = 0; j4 < 16; ++j4) {
        float4 t = *(const float4*)(W + (size_t)lane * stride + j4 * 4);
        wh[2 * j4 + 0] = half2_t{(_Float16)t.x, (_Float16)t.y};
        wh[2 * j4 + 1] = half2_t{(_Float16)t.z, (_Float16)t.w};
    }
}

// ---------------- CSR build ----------------

__global__ __launch_bounds__(256) void hist_kernel(const int* __restrict__ dst,
                                                   int* __restrict__ hist, int E) {
    int i = blockIdx.x * blockDim.x + threadIdx.x;
    for (; i < E; i += gridDim.x * blockDim.x)
        atomicAdd(&hist[dst[i]], 1);
}

template <bool PAD>
__global__ __launch_bounds__(256) void chunk_sum_kernel(const int* __restrict__ hist,
                                                        int* __restrict__ csum, int N) {
    __shared__ int wpart[4];
    const int base = blockIdx.x * 1024 + threadIdx.x * 4;
    int s = 0;
    if (base + 3 < N) {
        int4 t = *(const int4*)(hist + base);
        if (PAD) s = ((t.x+15)&~15) + ((t.y+15)&~15) + ((t.z+15)&~15) + ((t.w+15)&~15);
        else     s = t.x + t.y + t.z + t.w;
    } else {
#pragma unroll
        for (int j = 0; j < 4; ++j)
            if (base + j < N) { int v = hist[base + j]; s += PAD ? ((v+15)&~15) : v; }
    }
    s = wtotal64_i(s);
    if ((threadIdx.x & 63) == 0) wpart[threadIdx.x >> 6] = s;
    __syncthreads();
    if (threadIdx.x == 0) csum[blockIdx.x] = wpart[0] + wpart[1] + wpart[2] + wpart[3];
}

__global__ void chunk_offsets_kernel(const int* __restrict__ csum, int* __restrict__ coff,
                                     int* __restrict__ rowptr, int nchunk, int N) {
    const int lane = threadIdx.x;
    int carry = 0;
    for (int base = 0; base < nchunk; base += 64) {
        const int i = base + lane;
        int val = (i < nchunk) ? csum[i] : 0;
        int incl = val;
#pragma unroll
        for (int off = 1; off < 64; off <<= 1) {
            int t = __shfl_up(incl, off, 64);
            if (lane >= off) incl += t;
        }
        if (i < nchunk) coff[i] = incl - val + carry;
        carry += __shfl(incl, 63, 64);
    }
    if (lane == 0) rowptr[N] = carry;
}

template <bool PAD>
__global__ __launch_bounds__(256) void chunk_apply_kernel(
        const int* __restrict__ hist, const int* __restrict__ coff,
        int* __restrict__ rowptr, int* __restrict__ cursor, int N) {
    __shared__ int wpart[4];
    const int wv = threadIdx.x >> 6;
    const int lane = threadIdx.x & 63;
    const int base = blockIdx.x * 1024 + threadIdx.x * 4;
    int v0 = 0, v1 = 0, v2 = 0, v3 = 0;
    if (base + 3 < N) {
        int4 t = *(const int4*)(hist + base);
        v0 = t.x; v1 = t.y; v2 = t.z; v3 = t.w;
    } else {
        if (base + 0 < N) v0 = hist[base + 0];
        if (base + 1 < N) v1 = hist[base + 1];
        if (base + 2 < N) v2 = hist[base + 2];
        if (base + 3 < N) v3 = hist[base + 3];
    }
    if (PAD) { v0 = (v0+15)&~15; v1 = (v1+15)&~15; v2 = (v2+15)&~15; v3 = (v3+15)&~15; }
    const int s = v0 + v1 + v2 + v3;
    int incl = s;
#pragma unroll
    for (int off = 1; off < 64; off <<= 1) {
        int t = __shfl_up(incl, off, 64);
        if (lane >= off) incl += t;
    }
    if (lane == 63) wpart[wv] = incl;
    __syncthreads();
    int excl = coff[blockIdx.x] + incl - s;
    for (int w = 0; w < wv; ++w) excl += wpart[w];
    if (base + 0 < N) { rowptr[base + 0] = excl; cursor[base + 0] = excl; excl += v0; }
    if (base + 1 < N) { rowptr[base + 1] = excl; cursor[base + 1] = excl; excl += v1; }
    if (base + 2 < N) { rowptr[base + 2] = excl; cursor[base + 2] = excl; excl += v2; }
    if (base + 3 < N) { rowptr[base + 3] = excl; cursor[base + 3] = excl; excl += v3; }
}

// packed payload: .x = src index, .y = edge feature bits
__global__ __launch_bounds__(256) void scatter_kernel(
        const int* __restrict__ dst, const int* __restrict__ src,
        const float* __restrict__ ef, int* __restrict__ cursor,
        int2* __restrict__ ep, int E) {
    int i = blockIdx.x * blockDim.x + threadIdx.x;
    for (; i < E; i += gridDim.x * blockDim.x) {
        const int slot = atomicAdd(&cursor[dst[i]], 1);
        ep[slot] = make_int2(src[i], __float_as_int(ef[i]));
    }
}

// ---------------- fused node linear: RL segment + LL segment, one dispatch ----------------

__global__ __launch_bounds__(256, 4) void lin2_kernel(
        const float* __restrict__ XR, const float* __restrict__ WR,
        const float* __restrict__ bR, float* __restrict__ YR, int NR,
        const float* __restrict__ XL, const float* __restrict__ WL,
        float* __restrict__ YL, int NL, int nbR) {
    __shared__ __align__(16) _Float16 xbuf[4][EMB];
    const int wv = threadIdx.x >> 6;
    const int lane = threadIdx.x & 63;
    const bool isR = (int)blockIdx.x < nbR;
    const float* X = isR ? XR : XL;
    float* Y       = isR ? YR : YL;
    const int N    = isR ? NR : NL;
    const int b0   = isR ? 0 : nbR;
    const int nb   = isR ? nbR : (gridDim.x - nbR);
    half2_t wh[32];
    load_w_f16(isR ? WR : WL, EMB, lane, wh);
    const float bias = isR ? bR[lane] : 0.0f;
    const int nW = nb * 4;
    for (int n = ((int)blockIdx.x - b0) * 4 + wv; n < N; n += nW) {
        xbuf[wv][lane] = (_Float16)X[(size_t)n * EMB + lane];
        Y[(size_t)n * EMB + lane] = matvec_f16(xbuf[wv], wh, bias);
    }
}

// ---------------- edge stage: wave per node, MFMA over 16-edge groups ----------------
// A-frag: A[m = lane&15][k = (lane>>4)*8 + j]  (j=0..7; frag1 at k+32)
// B-frag: B[n = lane&15][k = (lane>>4)*8 + j]  = Wf[n][k]  (h @ Wf^T)
// C accumulates across all the node's groups; one cross-quad reduce + plain store.

__global__ __launch_bounds__(256, 3) void edge_mfma_kernel(
        const int* __restrict__ rp16, const int* __restrict__ deg,
        const int2* __restrict__ ep,
        const float* __restrict__ RL, const float* __restrict__ LL,
        const float* __restrict__ We, const float* __restrict__ g1,
        const float* __restrict__ b1, const float* __restrict__ Wf,
        float* __restrict__ AGG, int Nr) {
    const int lane = threadIdx.x & 63;
    const int col  = lane & 15;
    const int quad = lane >> 4;
    const int kb   = quad * 8;

    float we[16], gk[16], bk[16];
#pragma unroll
    for (int j = 0; j < 8; ++j) {
        we[j] = We[kb + j];       we[8 + j] = We[kb + 32 + j];
        gk[j] = g1[kb + j];       gk[8 + j] = g1[kb + 32 + j];
        bk[j] = b1[kb + j];       bk[8 + j] = b1[kb + 32 + j];
    }
    f16x8 B0[4], B1[4];
#pragma unroll
    for (int t = 0; t < 4; ++t) {
        const float* wrow = Wf + (size_t)(t * 16 + col) * EMB;
#pragma unroll
        for (int j = 0; j < 8; ++j) {
            B0[t][j] = (_Float16)wrow[kb + j];
            B1[t][j] = (_Float16)wrow[kb + 32 + j];
        }
    }

    const int nW = gridDim.x * 4;
    for (int n = blockIdx.x * 4 + (threadIdx.x >> 6); n < Nr; n += nW) {
        const int g0  = rp16[n] >> 4;
        const int g1e = rp16[n + 1] >> 4;
        const int dn  = deg[n];
        const float* rlrow = RL + (size_t)n * EMB;
        float rl16[16];
        *(float4*)&rl16[0]  = *(const float4*)(rlrow + kb);
        *(float4*)&rl16[4]  = *(const float4*)(rlrow + kb + 4);
        *(float4*)&rl16[8]  = *(const float4*)(rlrow + kb + 32);
        *(float4*)&rl16[12] = *(const float4*)(rlrow + kb + 36);

        f32x4 c0 = {0,0,0,0}, c1 = {0,0,0,0}, c2 = {0,0,0,0}, c3 = {0,0,0,0};
        for (int g = g0; g < g1e; ++g) {
            const int cnt = dn - ((g - g0) << 4);
            const bool live = col < cnt;
            const int2 p = ep[(g << 4) + col];
            const int s = live ? p.x : 0;
            const float f = live ? __int_as_float(p.y) : 0.0f;
            const float* llrow = LL + (size_t)s * EMB;
            float h[16];
            *(float4*)&h[0]  = *(const float4*)(llrow + kb);
            *(float4*)&h[4]  = *(const float4*)(llrow + kb + 4);
            *(float4*)&h[8]  = *(const float4*)(llrow + kb + 32);
            *(float4*)&h[12] = *(const float4*)(llrow + kb + 36);
            float ps = 0.0f, pq = 0.0f;
#pragma unroll
            for (int j = 0; j < 16; ++j) {
                h[j] = rl16[j] + h[j] + f * we[j];
                ps += h[j];
                pq += h[j] * h[j];
            }
            ps += __shfl_xor(ps, 16, 64); ps += __shfl_xor(ps, 32, 64);
            pq += __shfl_xor(pq, 16, 64); pq += __shfl_xor(pq, 32, 64);
            const float mean = ps * (1.0f / EMB);
            const float var  = pq * (1.0f / EMB) - mean * mean;
            const float rs   = rsqrtf(var + EPSLN);

            f16x8 A0, A1;
#pragma unroll
            for (int j = 0; j < 8; ++j) {
                float h0 = fmaxf((h[j]     - mean) * rs * gk[j]     + bk[j],     0.0f);
                float h1 = fmaxf((h[8 + j] - mean) * rs * gk[8 + j] + bk[8 + j], 0.0f);
                A0[j] = live ? (_Float16)h0 : (_Float16)0.0f;
                A1[j] = live ? (_Float16)h1 : (_Float16)0.0f;
            }
            c0 = __builtin_amdgcn_mfma_f32_16x16x32_f16(A0, B0[0], c0, 0, 0, 0);
            c0 = __builtin_amdgcn_mfma_f32_16x16x32_f16(A1, B1[0], c0, 0, 0, 0);
            c1 = __builtin_amdgcn_mfma_f32_16x16x32_f16(A0, B0[1], c1, 0, 0, 0);
            c1 = __builtin_amdgcn_mfma_f32_16x16x32_f16(A1, B1[1], c1, 0, 0, 0);
            c2 = __builtin_amdgcn_mfma_f32_16x16x32_f16(A0, B0[2], c2, 0, 0, 0);
            c2 = __builtin_amdgcn_mfma_f32_16x16x32_f16(A1, B1[2], c2, 0, 0, 0);
            c3 = __builtin_amdgcn_mfma_f32_16x16x32_f16(A0, B0[3], c3, 0, 0, 0);
            c3 = __builtin_amdgcn_mfma_f32_16x16x32_f16(A1, B1[3], c3, 0, 0, 0);
        }
        float s0 = (c0[0] + c0[1]) + (c0[2] + c0[3]);
        float s1 = (c1[0] + c1[1]) + (c1[2] + c1[3]);
        float s2 = (c2[0] + c2[1]) + (c2[2] + c2[3]);
        float s3 = (c3[0] + c3[1]) + (c3[2] + c3[3]);
        s0 += __shfl_xor(s0, 16, 64); s0 += __shfl_xor(s0, 32, 64);
        s1 += __shfl_xor(s1, 16, 64); s1 += __shfl_xor(s1, 32, 64);
        s2 += __shfl_xor(s2, 16, 64); s2 += __shfl_xor(s2, 32, 64);
        s3 += __shfl_xor(s3, 16, 64); s3 += __shfl_xor(s3, 32, 64);
        const float outv = (quad == 0) ? s0 : (quad == 1) ? s1 : (quad == 2) ? s2 : s3;
        AGG[(size_t)n * EMB + quad * 16 + col] = outv;
    }
}

// ---------------- fallback edge path (wave per node, dot2, packed ep) ----------------

__global__ __launch_bounds__(256, 4) void edge_csr_kernel(
        const int* __restrict__ rowptr, const int2* __restrict__ ep,
        const float* __restrict__ RL, const float* __restrict__ LL,
        const float* __restrict__ Wecol, const float* __restrict__ g1,
        const float* __restrict__ b1,
        const float* __restrict__ Wf, const float* __restrict__ bfp,
        float* __restrict__ AGG, int Nr) {
    __shared__ __align__(16) _Float16 hbuf[4][EMB];
    const int wv = threadIdx.x >> 6;
    const int lane = threadIdx.x & 63;
    half2_t wh[32];
    load_w_f16(Wf, EMB, lane, wh);
    const float we  = Wecol[lane];
    const float g   = g1[lane];
    const float bb  = b1[lane];
    const float bf_ = bfp[lane];
    const int nW = gridDim.x * 4;
    for (int n = blockIdx.x * 4 + wv; n < Nr; n += nW) {
        const int beg = rowptr[n];
        const int end = rowptr[n + 1];
        const float rl = RL[(size_t)n * EMB + lane];
        float acc = 0.0f;
        for (int idx = beg; idx < end; ++idx) {
            const int2 p = ep[idx];
            const float f = __int_as_float(p.y);
            float h = rl + LL[(size_t)p.x * EMB + lane] + f * we;
            const float s1 = wtotal64(h);
            const float s2 = wtotal64(h * h);
            const float m   = s1 * (1.0f / EMB);
            const float var = s2 * (1.0f / EMB) - m * m;
            float hn = fmaxf((h - m) * rsqrtf(var + EPSLN) * g + bb, 0.0f);
            hbuf[wv][lane] = (_Float16)hn;
            acc = matvec_f16(hbuf[wv], wh, acc);
        }
        AGG[(size_t)n * EMB + lane] = acc + (float)(end - beg) * bf_;
    }
}

// ---------------- fused output MLP (RB computed inline) ----------------
// z = LN(AGG + deg*bf); o = relu(Wo1a@z + Wo1b@right + bo1); right += Wo2@o + bo2

__global__ __launch_bounds__(256, 3) void out_kernel(
        const float* __restrict__ AGG, float* __restrict__ right,
        const float* __restrict__ g2, const float* __restrict__ b2,
        const float* __restrict__ Wo1, const float* __restrict__ Wo2,
        const float* __restrict__ bo1, const float* __restrict__ bo2,
        const int* __restrict__ deg, const float* __restrict__ bfp, int N) {
    __shared__ __align__(16) _Float16 zbuf[4][EMB];
    __shared__ __align__(16) _Float16 rbuf[4][EMB];
    __shared__ __align__(16) _Float16 obuf[4][EMB];
    const int wv = threadIdx.x >> 6;
    const int lane = threadIdx.x & 63;
    half2_t wh1[32], whB[32], wh2[32];
    load_w_f16(Wo1, 2 * EMB, lane, wh1);            // Wo1[:, 0:64]
    load_w_f16(Wo1 + EMB, 2 * EMB, lane, whB);      // Wo1[:, 64:128]
    load_w_f16(Wo2, EMB, lane, wh2);
    const float g   = g2[lane];
    const float bb  = b2[lane];
    const float bo1v = bo1[lane];
    const float bo2v = bo2[lane];
    const float bfv = deg ? bfp[lane] : 0.0f;
    const int nW = gridDim.x * 4;
    for (int n = blockIdx.x * 4 + wv; n < N; n += nW) {
        float a = AGG[(size_t)n * EMB + lane];
        if (deg) a += (float)deg[n] * bfv;          // per-edge bias folded: deg * bf
        const float rf = right[(size_t)n * EMB + lane];
        const float s1 = wtotal64(a);
        const float s2 = wtotal64(a * a);
        const float m   = s1 * (1.0f / EMB);
        const float var = s2 * (1.0f / EMB) - m * m;
        const float z = (a - m) * rsqrtf(var + EPSLN) * g + bb;
        zbuf[wv][lane] = (_Float16)z;
        rbuf[wv][lane] = (_Float16)rf;
        float acc = matvec_f16(zbuf[wv], wh1, bo1v);
        acc = matvec_f16(rbuf[wv], whB, acc);
        obuf[wv][lane] = (_Float16)fmaxf(acc, 0.0f);
        float acc2 = matvec_f16(obuf[wv], wh2, bo2v);
        right[(size_t)n * EMB + lane] = rf + acc2;
    }
}

extern "C" void kernel_launch(void* const* d_in, const int* in_sizes, int n_in,
                              void* d_out, int out_size, void* d_ws, size_t ws_size,
                              hipStream_t stream) {
    const float* cf  = (const float*)d_in[0];
    const float* vfp = (const float*)d_in[1];
    const int*   ei  = (const int*)d_in[2];
    const float* ef  = (const float*)d_in[3];
    const float* Wl  = (const float*)d_in[4];
    const float* bl  = (const float*)d_in[5];
    const float* We  = (const float*)d_in[6];
    const float* Wr  = (const float*)d_in[7];
    const float* g1  = (const float*)d_in[8];
    const float* b1  = (const float*)d_in[9];
    const float* Wf  = (const float*)d_in[10];
    const float* bfp = (const float*)d_in[11];
    const float* g2  = (const float*)d_in[12];
    const float* b2  = (const float*)d_in[13];
    const float* Wo1 = (const float*)d_in[14];
    const float* bo1 = (const float*)d_in[15];
    const float* Wo2 = (const float*)d_in[16];
    const float* bo2 = (const float*)d_in[17];

    float* c = (float*)d_out;
    float* v = c + (size_t)NCON * EMB;
    (void)hipMemcpyAsync(c, cf,  (size_t)NCON * EMB * sizeof(float), hipMemcpyDeviceToDevice, stream);
    (void)hipMemcpyAsync(v, vfp, (size_t)NVAR * EMB * sizeof(float), hipMemcpyDeviceToDevice, stream);

    float* wsf = (float*)d_ws;
    size_t off = 0;
    float* AGG = wsf + off; off += (size_t)NVAR * EMB;
    float* RL  = wsf + off; off += (size_t)NVAR * EMB;
    float* LL  = wsf + off; off += (size_t)NVAR * EMB;
    int* degC  = (int*)(wsf + off); off += NCON;
    int* degV  = (int*)(wsf + off); off += NVAR;
    int* rp16C = (int*)(wsf + off); off += NCON + 4;
    int* curC  = (int*)(wsf + off); off += NCON;
    int* rp16V = (int*)(wsf + off); off += NVAR + 4;
    int* curV  = (int*)(wsf + off); off += NVAR;
    int* csumC = (int*)(wsf + off); off += 128;
    int* coffC = (int*)(wsf + off); off += 128;
    int* csumV = (int*)(wsf + off); off += 128;
    int* coffV = (int*)(wsf + off); off += 128;
    size_t off_edges = off;
    int2* epC = (int2*)(wsf + off); off += (size_t)2 * PADEC;
    int2* epV = (int2*)(wsf + off); off += (size_t)2 * PADEV;
    const bool use_mfma = ws_size >= off * sizeof(float);
    if (!use_mfma) {
        off = off_edges;
        epC = (int2*)(wsf + off); off += (size_t)2 * NEDGE;
        epV = (int2*)(wsf + off); off += (size_t)2 * NEDGE;
    }
    const bool use_csr = ws_size >= off * sizeof(float);

    const int* ci = ei;
    const int* vi = ei + NEDGE;

    const dim3 blk(256);
    const int NB = 2048;
    const int NBL = 1536;
    const int nchC = (NCON + 1023) / 1024;   // 49
    const int nchV = (NVAR + 1023) / 1024;   // 98

    if (use_csr) {
        (void)hipMemsetAsync(degC, 0, NCON * sizeof(int), stream);
        (void)hipMemsetAsync(degV, 0, NVAR * sizeof(int), stream);
        hist_kernel<<<1024, blk, 0, stream>>>(ci, degC, NEDGE);
        hist_kernel<<<1024, blk, 0, stream>>>(vi, degV, NEDGE);
        if (use_mfma) {
            chunk_sum_kernel<true><<<nchC, blk, 0, stream>>>(degC, csumC, NCON);
            chunk_sum_kernel<true><<<nchV, blk, 0, stream>>>(degV, csumV, NVAR);
            chunk_offsets_kernel<<<1, 64, 0, stream>>>(csumC, coffC, rp16C, nchC, NCON);
            chunk_offsets_kernel<<<1, 64, 0, stream>>>(csumV, coffV, rp16V, nchV, NVAR);
            chunk_apply_kernel<true><<<nchC, blk, 0, stream>>>(degC, coffC, rp16C, curC, NCON);
            chunk_apply_kernel<true><<<nchV, blk, 0, stream>>>(degV, coffV, rp16V, curV, NVAR);
        } else {
            chunk_sum_kernel<false><<<nchC, blk, 0, stream>>>(degC, csumC, NCON);
            chunk_sum_kernel<false><<<nchV, blk, 0, stream>>>(degV, csumV, NVAR);
            chunk_offsets_kernel<<<1, 64, 0, stream>>>(csumC, coffC, rp16C, nchC, NCON);
            chunk_offsets_kernel<<<1, 64, 0, stream>>>(csumV, coffV, rp16V, nchV, NVAR);
            chunk_apply_kernel<false><<<nchC, blk, 0, stream>>>(degC, coffC, rp16C, curC, NCON);
            chunk_apply_kernel<false><<<nchV, blk, 0, stream>>>(degV, coffV, rp16V, curV, NVAR);
        }
        scatter_kernel<<<1024, blk, 0, stream>>>(ci, vi, ef, curC, epC, NEDGE);
        scatter_kernel<<<1024, blk, 0, stream>>>(vi, ci, ef, curV, epV, NEDGE);
    }

    for (int k = 0; k < 4; ++k) {
        const bool v2c = ((k & 1) == 0);
        float* right   = v2c ? c : v;
        float* left    = v2c ? v : c;
        const int Nr   = v2c ? NCON : NVAR;
        const int Nl   = v2c ? NVAR : NCON;
        const int nbR  = v2c ? NBL / 3 : 2 * NBL / 3;   // split blocks ~ Nr : Nl

        lin2_kernel<<<NBL, blk, 0, stream>>>(
            right, Wl + (size_t)k * EMB * EMB, bl + (size_t)k * EMB, RL, Nr,
            left,  Wr + (size_t)k * EMB * EMB, LL, Nl, nbR);

        const int* degp = v2c ? degC : degV;
        if (use_mfma) {
            edge_mfma_kernel<<<NB, blk, 0, stream>>>(
                v2c ? rp16C : rp16V, degp, v2c ? epC : epV,
                RL, LL, We + (size_t)k * EMB,
                g1 + (size_t)k * EMB, b1 + (size_t)k * EMB,
                Wf + (size_t)k * EMB * EMB, AGG, Nr);
        } else {
            edge_csr_kernel<<<NB, blk, 0, stream>>>(
                v2c ? rp16C : rp16V, v2c ? epC : epV,
                RL, LL, We + (size_t)k * EMB,
                g1 + (size_t)k * EMB, b1 + (size_t)k * EMB,
                Wf + (size_t)k * EMB * EMB, bfp + (size_t)k * EMB, AGG, Nr);
        }
        out_kernel<<<NB, blk, 0, stream>>>(AGG, right,
                                           g2 + (size_t)k * EMB, b2 + (size_t)k * EMB,
                                           Wo1 + (size_t)k * EMB * 2 * EMB,
                                           Wo2 + (size_t)k * EMB * EMB,
                                           bo1 + (size_t)k * EMB, bo2 + (size_t)k * EMB,
                                           use_mfma ? degp : nullptr,
                                           bfp + (size_t)k * EMB, Nr);
    }
}

// Round 7
// 1322.169 us; speedup vs baseline: 3.4594x; 1.1528x over previous
//
#include <hip/hip_runtime.h>

#define EMB   64
#define NCON  50000
#define NVAR  100000
#define NEDGE 1600000
#define EPSLN 1e-5f

// padded-CSR capacities (worst case: every node pads +15)
#define PADEC (NEDGE + 15 * NCON)    // 2,350,000
#define PADEV (NEDGE + 15 * NVAR)    // 3,100,000

typedef _Float16 half2_t __attribute__((ext_vector_type(2)));
typedef _Float16 f16x8  __attribute__((ext_vector_type(8)));

// ---- wave-total via DPP (no DS ops) ----
template <int CTRL, int RMASK>
__device__ __forceinline__ float dpp_add_f(float x) {
    int m = __builtin_amdgcn_update_dpp(0, __builtin_bit_cast(int, x), CTRL, RMASK, 0xf, true);
    return x + __builtin_bit_cast(float, m);
}
__device__ __forceinline__ float wtotal64(float x) {
    x = dpp_add_f<0x111, 0xf>(x);
    x = dpp_add_f<0x112, 0xf>(x);
    x = dpp_add_f<0x114, 0xf>(x);
    x = dpp_add_f<0x118, 0xf>(x);
    x = dpp_add_f<0x142, 0xa>(x);
    x = dpp_add_f<0x143, 0xc>(x);
    return __builtin_bit_cast(float, __builtin_amdgcn_readlane(__builtin_bit_cast(int, x), 63));
}
template <int CTRL, int RMASK>
__device__ __forceinline__ int dpp_add_i(int x) {
    return x + __builtin_amdgcn_update_dpp(0, x, CTRL, RMASK, 0xf, true);
}
__device__ __forceinline__ int wtotal64_i(int x) {
    x = dpp_add_i<0x111, 0xf>(x);
    x = dpp_add_i<0x112, 0xf>(x);
    x = dpp_add_i<0x114, 0xf>(x);
    x = dpp_add_i<0x118, 0xf>(x);
    x = dpp_add_i<0x142, 0xa>(x);
    x = dpp_add_i<0x143, 0xc>(x);
    return __builtin_amdgcn_readlane(x, 63);
}

__device__ __forceinline__ float dot2f(half2_t a, half2_t b, float c) {
    return __builtin_amdgcn_fdot2(a, b, c, false);
}

__device__ __forceinline__ half2_t hmax2(half2_t a, half2_t b) {
#if defined(__has_builtin) && __has_builtin(__builtin_elementwise_max)
    return __builtin_elementwise_max(a, b);
#else
    half2_t r;
    r.x = a.x > b.x ? a.x : b.x;
    r.y = a.y > b.y ? a.y : b.y;
    return r;
#endif
}

// 8 x ds_read_b128 + 32 x v_dot2 with 4 independent accumulator chains
__device__ __forceinline__ float matvec_f16(const _Float16* __restrict__ buf,
                                            const half2_t* __restrict__ wh, float acc) {
    const float4* hp4 = (const float4*)buf;
    float a0 = acc, a1 = 0.0f, a2 = 0.0f, a3 = 0.0f;
#pragma unroll
    for (int j4 = 0; j4 < 8; ++j4) {
        float4 t = hp4[j4];
        a0 = dot2f(wh[4 * j4 + 0], __builtin_bit_cast(half2_t, t.x), a0);
        a1 = dot2f(wh[4 * j4 + 1], __builtin_bit_cast(half2_t, t.y), a1);
        a2 = dot2f(wh[4 * j4 + 2], __builtin_bit_cast(half2_t, t.z), a2);
        a3 = dot2f(wh[4 * j4 + 3], __builtin_bit_cast(half2_t, t.w), a3);
    }
    return (a0 + a1) + (a2 + a3);
}

__device__ __forceinline__ void load_w_f16(const float* __restrict__ W, int stride,
                                           int lane, half2_t* wh) {
#pragma unroll
    for (int j4 = 0; j4 < 16; ++j4) {
        float4 t = *(const float4*)(W + (size_t)lane * stride + j4 * 4);
        wh[2 * j4 + 0] = half2_t{(_Float16)t.x, (_Float16)t.y};
        wh[2 * j4 + 1] = half2_t{(_Float16)t.z, (_Float16)t.w};
    }
}

// ---------------- CSR build ----------------

// both directions in one pass
__global__ __launch_bounds__(256) void hist2_kernel(
        const int* __restrict__ ci, const int* __restrict__ vi,
        int* __restrict__ degC, int* __restrict__ degV, int E) {
    int i = blockIdx.x * blockDim.x + threadIdx.x;
    for (; i < E; i += gridDim.x * blockDim.x) {
        atomicAdd(&degC[ci[i]], 1);
        atomicAdd(&degV[vi[i]], 1);
    }
}

template <bool PAD>
__global__ __launch_bounds__(256) void chunk_sum_kernel(const int* __restrict__ hist,
                                                        int* __restrict__ csum, int N) {
    __shared__ int wpart[4];
    const int base = blockIdx.x * 1024 + threadIdx.x * 4;
    int s = 0;
    if (base + 3 < N) {
        int4 t = *(const int4*)(hist + base);
        if (PAD) s = ((t.x+15)&~15) + ((t.y+15)&~15) + ((t.z+15)&~15) + ((t.w+15)&~15);
        else     s = t.x + t.y + t.z + t.w;
    } else {
#pragma unroll
        for (int j = 0; j < 4; ++j)
            if (base + j < N) { int v = hist[base + j]; s += PAD ? ((v+15)&~15) : v; }
    }
    s = wtotal64_i(s);
    if ((threadIdx.x & 63) == 0) wpart[threadIdx.x >> 6] = s;
    __syncthreads();
    if (threadIdx.x == 0) csum[blockIdx.x] = wpart[0] + wpart[1] + wpart[2] + wpart[3];
}

__global__ void chunk_offsets_kernel(const int* __restrict__ csum, int* __restrict__ coff,
                                     int* __restrict__ rowptr, int nchunk, int N) {
    const int lane = threadIdx.x;
    int carry = 0;
    for (int base = 0; base < nchunk; base += 64) {
        const int i = base + lane;
        int val = (i < nchunk) ? csum[i] : 0;
        int incl = val;
#pragma unroll
        for (int off = 1; off < 64; off <<= 1) {
            int t = __shfl_up(incl, off, 64);
            if (lane >= off) incl += t;
        }
        if (i < nchunk) coff[i] = incl - val + carry;
        carry += __shfl(incl, 63, 64);
    }
    if (lane == 0) rowptr[N] = carry;
}

template <bool PAD>
__global__ __launch_bounds__(256) void chunk_apply_kernel(
        const int* __restrict__ hist, const int* __restrict__ coff,
        int* __restrict__ rowptr, int* __restrict__ cursor, int N) {
    __shared__ int wpart[4];
    const int wv = threadIdx.x >> 6;
    const int lane = threadIdx.x & 63;
    const int base = blockIdx.x * 1024 + threadIdx.x * 4;
    int v0 = 0, v1 = 0, v2 = 0, v3 = 0;
    if (base + 3 < N) {
        int4 t = *(const int4*)(hist + base);
        v0 = t.x; v1 = t.y; v2 = t.z; v3 = t.w;
    } else {
        if (base + 0 < N) v0 = hist[base + 0];
        if (base + 1 < N) v1 = hist[base + 1];
        if (base + 2 < N) v2 = hist[base + 2];
        if (base + 3 < N) v3 = hist[base + 3];
    }
    if (PAD) { v0 = (v0+15)&~15; v1 = (v1+15)&~15; v2 = (v2+15)&~15; v3 = (v3+15)&~15; }
    const int s = v0 + v1 + v2 + v3;
    int incl = s;
#pragma unroll
    for (int off = 1; off < 64; off <<= 1) {
        int t = __shfl_up(incl, off, 64);
        if (lane >= off) incl += t;
    }
    if (lane == 63) wpart[wv] = incl;
    __syncthreads();
    int excl = coff[blockIdx.x] + incl - s;
    for (int w = 0; w < wv; ++w) excl += wpart[w];
    if (base + 0 < N) { rowptr[base + 0] = excl; cursor[base + 0] = excl; excl += v0; }
    if (base + 1 < N) { rowptr[base + 1] = excl; cursor[base + 1] = excl; excl += v1; }
    if (base + 2 < N) { rowptr[base + 2] = excl; cursor[base + 2] = excl; excl += v2; }
    if (base + 3 < N) { rowptr[base + 3] = excl; cursor[base + 3] = excl; excl += v3; }
}

// both directions in one pass; payload .x = src, .y = edge-feature bits
__global__ __launch_bounds__(256) void scatter2_kernel(
        const int* __restrict__ ci, const int* __restrict__ vi,
        const float* __restrict__ ef,
        int* __restrict__ curC, int* __restrict__ curV,
        int2* __restrict__ epC, int2* __restrict__ epV, int E) {
    int i = blockIdx.x * blockDim.x + threadIdx.x;
    for (; i < E; i += gridDim.x * blockDim.x) {
        const int cd = ci[i];
        const int vd = vi[i];
        const int fb = __float_as_int(ef[i]);
        const int sc = atomicAdd(&curC[cd], 1);
        epC[sc] = make_int2(vd, fb);
        const int sv = atomicAdd(&curV[vd], 1);
        epV[sv] = make_int2(cd, fb);
    }
}

// ---------------- fused node linear: RL segment + LL segment -> f16 ----------------

__global__ __launch_bounds__(256, 4) void lin2_kernel(
        const float* __restrict__ XR, const float* __restrict__ WR,
        const float* __restrict__ bR, _Float16* __restrict__ YR, int NR,
        const float* __restrict__ XL, const float* __restrict__ WL,
        _Float16* __restrict__ YL, int NL, int nbR) {
    __shared__ __align__(16) _Float16 xbuf[4][EMB];
    const int wv = threadIdx.x >> 6;
    const int lane = threadIdx.x & 63;
    const bool isR = (int)blockIdx.x < nbR;
    const float* X = isR ? XR : XL;
    _Float16* Y    = isR ? YR : YL;
    const int N    = isR ? NR : NL;
    const int b0   = isR ? 0 : nbR;
    const int nb   = isR ? nbR : (gridDim.x - nbR);
    half2_t wh[32];
    load_w_f16(isR ? WR : WL, EMB, lane, wh);
    const float bias = isR ? bR[lane] : 0.0f;
    const int nW = nb * 4;
    for (int n = ((int)blockIdx.x - b0) * 4 + wv; n < N; n += nW) {
        xbuf[wv][lane] = (_Float16)X[(size_t)n * EMB + lane];
        Y[(size_t)n * EMB + lane] = (_Float16)matvec_f16(xbuf[wv], wh, bias);
    }
}

// ---------------- edge stage: wave per node, abar accumulate, Wf once/node ----------------
// Key identity: sum_e relu(LN(h_e)) @ Wf^T = (sum_e relu(LN(h_e))) @ Wf^T  (matvec is linear).
// Layout: 16 edges at a time; lane (quad,col): col = edge slot, quad = k-slice (kb..kb+7,
// kb+32..kb+39). LN stats reduce across quads (shfl_xor 16,32). abar accumulated in f32,
// reduced across cols (butterfly), then one 64x64 matvec per node via LDS broadcast.

__global__ __launch_bounds__(256, 4) void edge_abar_kernel(
        const int* __restrict__ rp16, const int* __restrict__ deg,
        const int2* __restrict__ ep,
        const _Float16* __restrict__ RL, const _Float16* __restrict__ LL,
        const float* __restrict__ We, const float* __restrict__ g1,
        const float* __restrict__ b1, const float* __restrict__ Wf,
        const float* __restrict__ bfp, float* __restrict__ AGG, int Nr) {
    __shared__ __align__(16) _Float16 abuf[4][EMB];
    const int wv   = threadIdx.x >> 6;
    const int lane = threadIdx.x & 63;
    const int col  = lane & 15;
    const int quad = lane >> 4;
    const int kb   = quad * 8;

    half2_t weh[8], gkh[8], bkh[8];
#pragma unroll
    for (int j = 0; j < 4; ++j) {
        weh[j]     = half2_t{(_Float16)We[kb + 2*j],      (_Float16)We[kb + 2*j + 1]};
        weh[4 + j] = half2_t{(_Float16)We[kb + 32 + 2*j], (_Float16)We[kb + 32 + 2*j + 1]};
        gkh[j]     = half2_t{(_Float16)g1[kb + 2*j],      (_Float16)g1[kb + 2*j + 1]};
        gkh[4 + j] = half2_t{(_Float16)g1[kb + 32 + 2*j], (_Float16)g1[kb + 32 + 2*j + 1]};
        bkh[j]     = half2_t{(_Float16)b1[kb + 2*j],      (_Float16)b1[kb + 2*j + 1]};
        bkh[4 + j] = half2_t{(_Float16)b1[kb + 32 + 2*j], (_Float16)b1[kb + 32 + 2*j + 1]};
    }
    half2_t whF[32];
    load_w_f16(Wf, EMB, lane, whF);
    const float bfv = bfp[lane];

    const int nW = gridDim.x * 4;
    for (int n = blockIdx.x * 4 + wv; n < Nr; n += nW) {
        const int g0  = rp16[n] >> 4;
        const int g1e = rp16[n + 1] >> 4;
        const int dn  = deg[n];
        half2_t rl2[8];
        *(f16x8*)&rl2[0] = *(const f16x8*)(RL + (size_t)n * EMB + kb);
        *(f16x8*)&rl2[4] = *(const f16x8*)(RL + (size_t)n * EMB + kb + 32);
        float acc[16];
#pragma unroll
        for (int j = 0; j < 16; ++j) acc[j] = 0.0f;

        if (g0 < g1e) {
            // prefetch first group
            bool livN = col < dn;
            int2 p = ep[(g0 << 4) + col];
            int sN = livN ? p.x : 0;
            float fN = livN ? __int_as_float(p.y) : 0.0f;
            f16x8 llaN = *(const f16x8*)(LL + (size_t)sN * EMB + kb);
            f16x8 llbN = *(const f16x8*)(LL + (size_t)sN * EMB + kb + 32);

            for (int g = g0; g < g1e; ++g) {
                const bool liv = livN;
                const float f = fN;
                half2_t h2[8];
                *(f16x8*)&h2[0] = llaN;
                *(f16x8*)&h2[4] = llbN;
                if (g + 1 < g1e) {
                    const int cnt = dn - ((g + 1 - g0) << 4);
                    livN = col < cnt;
                    p = ep[((g + 1) << 4) + col];
                    const int s2 = livN ? p.x : 0;
                    fN = livN ? __int_as_float(p.y) : 0.0f;
                    llaN = *(const f16x8*)(LL + (size_t)s2 * EMB + kb);
                    llbN = *(const f16x8*)(LL + (size_t)s2 * EMB + kb + 32);
                }
                const _Float16 fh = (_Float16)f;
                const half2_t f2 = half2_t{fh, fh};
                const half2_t one2 = half2_t{(_Float16)1.0f, (_Float16)1.0f};
                float ps = 0.0f, pq = 0.0f;
#pragma unroll
                for (int j = 0; j < 8; ++j) {
                    h2[j] = (h2[j] + rl2[j]) + f2 * weh[j];
                    ps = dot2f(h2[j], one2, ps);
                    pq = dot2f(h2[j], h2[j], pq);
                }
                ps += __shfl_xor(ps, 16, 64); ps += __shfl_xor(ps, 32, 64);
                pq += __shfl_xor(pq, 16, 64); pq += __shfl_xor(pq, 32, 64);
                const float mean = ps * (1.0f / EMB);
                const float var  = pq * (1.0f / EMB) - mean * mean;
                const float rs   = rsqrtf(var + EPSLN);
                const _Float16 rsh = (_Float16)rs;
                const _Float16 mnh = (_Float16)mean;
                const half2_t rs2 = half2_t{rsh, rsh};
                const half2_t mn2 = half2_t{mnh, mnh};
                const half2_t z2  = half2_t{(_Float16)0.0f, (_Float16)0.0f};
                if (liv) {
#pragma unroll
                    for (int j = 0; j < 8; ++j) {
                        const half2_t sc = gkh[j] * rs2;
                        half2_t a = (h2[j] - mn2) * sc + bkh[j];
                        a = hmax2(a, z2);
                        acc[2*j]   += (float)a.x;
                        acc[2*j+1] += (float)a.y;
                    }
                }
            }
        }
        // reduce abar partials across the 16 cols of each quad
#pragma unroll
        for (int st = 1; st < 16; st <<= 1) {
#pragma unroll
            for (int j = 0; j < 16; ++j)
                acc[j] += __shfl_xor(acc[j], st, 64);
        }
        // lane's element of abar: acc[col] maps to k = (col<8) ? kb+col : kb+32+(col-8)
        abuf[wv][(col < 8) ? (kb + col) : (kb + 24 + col)] = (_Float16)acc[col];
        // agg = abar @ Wf^T + deg*bf   (one matvec per node)
        AGG[(size_t)n * EMB + lane] = matvec_f16(abuf[wv], whF, (float)dn * bfv);
    }
}

// ---------------- fallback edge path (wave per node, dot2, f16 RL/LL) ----------------

__global__ __launch_bounds__(256, 4) void edge_csr_kernel(
        const int* __restrict__ rowptr, const int2* __restrict__ ep,
        const _Float16* __restrict__ RL, const _Float16* __restrict__ LL,
        const float* __restrict__ Wecol, const float* __restrict__ g1,
        const float* __restrict__ b1,
        const float* __restrict__ Wf, const float* __restrict__ bfp,
        float* __restrict__ AGG, int Nr) {
    __shared__ __align__(16) _Float16 hbuf[4][EMB];
    const int wv = threadIdx.x >> 6;
    const int lane = threadIdx.x & 63;
    half2_t wh[32];
    load_w_f16(Wf, EMB, lane, wh);
    const float we  = Wecol[lane];
    const float g   = g1[lane];
    const float bb  = b1[lane];
    const float bf_ = bfp[lane];
    const int nW = gridDim.x * 4;
    for (int n = blockIdx.x * 4 + wv; n < Nr; n += nW) {
        const int beg = rowptr[n];
        const int end = rowptr[n + 1];
        const float rl = (float)RL[(size_t)n * EMB + lane];
        float acc = 0.0f;
        for (int idx = beg; idx < end; ++idx) {
            const int2 p = ep[idx];
            const float f = __int_as_float(p.y);
            float h = rl + (float)LL[(size_t)p.x * EMB + lane] + f * we;
            const float s1 = wtotal64(h);
            const float s2 = wtotal64(h * h);
            const float m   = s1 * (1.0f / EMB);
            const float var = s2 * (1.0f / EMB) - m * m;
            float hn = fmaxf((h - m) * rsqrtf(var + EPSLN) * g + bb, 0.0f);
            hbuf[wv][lane] = (_Float16)hn;
            acc = matvec_f16(hbuf[wv], wh, acc);
        }
        AGG[(size_t)n * EMB + lane] = acc + (float)(end - beg) * bf_;
    }
}

// ---------------- fused output MLP ----------------
// z = LN(AGG); o = relu(Wo1a@z + Wo1b@right + bo1); right += Wo2@o + bo2

__global__ __launch_bounds__(256, 3) void out_kernel(
        const float* __restrict__ AGG, float* __restrict__ right,
        const float* __restrict__ g2, const float* __restrict__ b2,
        const float* __restrict__ Wo1, const float* __restrict__ Wo2,
        const float* __restrict__ bo1, const float* __restrict__ bo2, int N) {
    __shared__ __align__(16) _Float16 zbuf[4][EMB];
    __shared__ __align__(16) _Float16 rbuf[4][EMB];
    __shared__ __align__(16) _Float16 obuf[4][EMB];
    const int wv = threadIdx.x >> 6;
    const int lane = threadIdx.x & 63;
    half2_t wh1[32], whB[32], wh2[32];
    load_w_f16(Wo1, 2 * EMB, lane, wh1);            // Wo1[:, 0:64]
    load_w_f16(Wo1 + EMB, 2 * EMB, lane, whB);      // Wo1[:, 64:128]
    load_w_f16(Wo2, EMB, lane, wh2);
    const float g    = g2[lane];
    const float bb   = b2[lane];
    const float bo1v = bo1[lane];
    const float bo2v = bo2[lane];
    const int nW = gridDim.x * 4;
    for (int n = blockIdx.x * 4 + wv; n < N; n += nW) {
        const float a = AGG[(size_t)n * EMB + lane];
        const float rf = right[(size_t)n * EMB + lane];
        const float s1 = wtotal64(a);
        const float s2 = wtotal64(a * a);
        const float m   = s1 * (1.0f / EMB);
        const float var = s2 * (1.0f / EMB) - m * m;
        const float z = (a - m) * rsqrtf(var + EPSLN) * g + bb;
        zbuf[wv][lane] = (_Float16)z;
        rbuf[wv][lane] = (_Float16)rf;
        float acc = matvec_f16(zbuf[wv], wh1, bo1v);
        acc = matvec_f16(rbuf[wv], whB, acc);
        obuf[wv][lane] = (_Float16)fmaxf(acc, 0.0f);
        float acc2 = matvec_f16(obuf[wv], wh2, bo2v);
        right[(size_t)n * EMB + lane] = rf + acc2;
    }
}

extern "C" void kernel_launch(void* const* d_in, const int* in_sizes, int n_in,
                              void* d_out, int out_size, void* d_ws, size_t ws_size,
                              hipStream_t stream) {
    const float* cf  = (const float*)d_in[0];
    const float* vfp = (const float*)d_in[1];
    const int*   ei  = (const int*)d_in[2];
    const float* ef  = (const float*)d_in[3];
    const float* Wl  = (const float*)d_in[4];
    const float* bl  = (const float*)d_in[5];
    const float* We  = (const float*)d_in[6];
    const float* Wr  = (const float*)d_in[7];
    const float* g1  = (const float*)d_in[8];
    const float* b1  = (const float*)d_in[9];
    const float* Wf  = (const float*)d_in[10];
    const float* bfp = (const float*)d_in[11];
    const float* g2  = (const float*)d_in[12];
    const float* b2  = (const float*)d_in[13];
    const float* Wo1 = (const float*)d_in[14];
    const float* bo1 = (const float*)d_in[15];
    const float* Wo2 = (const float*)d_in[16];
    const float* bo2 = (const float*)d_in[17];

    float* c = (float*)d_out;
    float* v = c + (size_t)NCON * EMB;
    (void)hipMemcpyAsync(c, cf,  (size_t)NCON * EMB * sizeof(float), hipMemcpyDeviceToDevice, stream);
    (void)hipMemcpyAsync(v, vfp, (size_t)NVAR * EMB * sizeof(float), hipMemcpyDeviceToDevice, stream);

    float* wsf = (float*)d_ws;
    size_t off = 0;
    float* AGG = wsf + off; off += (size_t)NVAR * EMB;
    _Float16* RL = (_Float16*)(wsf + off); off += (size_t)NVAR * EMB / 2;   // f16
    _Float16* LL = (_Float16*)(wsf + off); off += (size_t)NVAR * EMB / 2;   // f16
    int* degC  = (int*)(wsf + off); off += NCON;
    int* degV  = (int*)(wsf + off); off += NVAR;
    int* rp16C = (int*)(wsf + off); off += NCON + 4;
    int* curC  = (int*)(wsf + off); off += NCON;
    int* rp16V = (int*)(wsf + off); off += NVAR + 4;
    int* curV  = (int*)(wsf + off); off += NVAR;
    int* csumC = (int*)(wsf + off); off += 128;
    int* coffC = (int*)(wsf + off); off += 128;
    int* csumV = (int*)(wsf + off); off += 128;
    int* coffV = (int*)(wsf + off); off += 128;
    size_t off_edges = off;
    int2* epC = (int2*)(wsf + off); off += (size_t)2 * PADEC;
    int2* epV = (int2*)(wsf + off); off += (size_t)2 * PADEV;
    const bool use_mfma = ws_size >= off * sizeof(float);
    if (!use_mfma) {
        off = off_edges;
        epC = (int2*)(wsf + off); off += (size_t)2 * NEDGE;
        epV = (int2*)(wsf + off); off += (size_t)2 * NEDGE;
    }
    const bool use_csr = ws_size >= off * sizeof(float);
    (void)use_csr;

    const int* ci = ei;
    const int* vi = ei + NEDGE;

    const dim3 blk(256);
    const int NB = 2048;
    const int NBL = 1536;
    const int nchC = (NCON + 1023) / 1024;   // 49
    const int nchV = (NVAR + 1023) / 1024;   // 98

    (void)hipMemsetAsync(degC, 0, NCON * sizeof(int), stream);
    (void)hipMemsetAsync(degV, 0, NVAR * sizeof(int), stream);
    hist2_kernel<<<1024, blk, 0, stream>>>(ci, vi, degC, degV, NEDGE);
    if (use_mfma) {
        chunk_sum_kernel<true><<<nchC, blk, 0, stream>>>(degC, csumC, NCON);
        chunk_sum_kernel<true><<<nchV, blk, 0, stream>>>(degV, csumV, NVAR);
        chunk_offsets_kernel<<<1, 64, 0, stream>>>(csumC, coffC, rp16C, nchC, NCON);
        chunk_offsets_kernel<<<1, 64, 0, stream>>>(csumV, coffV, rp16V, nchV, NVAR);
        chunk_apply_kernel<true><<<nchC, blk, 0, stream>>>(degC, coffC, rp16C, curC, NCON);
        chunk_apply_kernel<true><<<nchV, blk, 0, stream>>>(degV, coffV, rp16V, curV, NVAR);
    } else {
        chunk_sum_kernel<false><<<nchC, blk, 0, stream>>>(degC, csumC, NCON);
        chunk_sum_kernel<false><<<nchV, blk, 0, stream>>>(degV, csumV, NVAR);
        chunk_offsets_kernel<<<1, 64, 0, stream>>>(csumC, coffC, rp16C, nchC, NCON);
        chunk_offsets_kernel<<<1, 64, 0, stream>>>(csumV, coffV, rp16V, nchV, NVAR);
        chunk_apply_kernel<false><<<nchC, blk, 0, stream>>>(degC, coffC, rp16C, curC, NCON);
        chunk_apply_kernel<false><<<nchV, blk, 0, stream>>>(degV, coffV, rp16V, curV, NVAR);
    }
    scatter2_kernel<<<1024, blk, 0, stream>>>(ci, vi, ef, curC, curV, epC, epV, NEDGE);

    for (int k = 0; k < 4; ++k) {
        const bool v2c = ((k & 1) == 0);
        float* right   = v2c ? c : v;
        float* left    = v2c ? v : c;
        const int Nr   = v2c ? NCON : NVAR;
        const int Nl   = v2c ? NVAR : NCON;
        const int nbR  = v2c ? NBL / 3 : 2 * NBL / 3;   // split blocks ~ Nr : Nl

        lin2_kernel<<<NBL, blk, 0, stream>>>(
            right, Wl + (size_t)k * EMB * EMB, bl + (size_t)k * EMB, RL, Nr,
            left,  Wr + (size_t)k * EMB * EMB, LL, Nl, nbR);

        if (use_mfma) {
            edge_abar_kernel<<<NB, blk, 0, stream>>>(
                v2c ? rp16C : rp16V, v2c ? degC : degV, v2c ? epC : epV,
                RL, LL, We + (size_t)k * EMB,
                g1 + (size_t)k * EMB, b1 + (size_t)k * EMB,
                Wf + (size_t)k * EMB * EMB, bfp + (size_t)k * EMB, AGG, Nr);
        } else {
            edge_csr_kernel<<<NB, blk, 0, stream>>>(
                v2c ? rp16C : rp16V, v2c ? epC : epV,
                RL, LL, We + (size_t)k * EMB,
                g1 + (size_t)k * EMB, b1 + (size_t)k * EMB,
                Wf + (size_t)k * EMB * EMB, bfp + (size_t)k * EMB, AGG, Nr);
        }
        out_kernel<<<NB, blk, 0, stream>>>(AGG, right,
                                           g2 + (size_t)k * EMB, b2 + (size_t)k * EMB,
                                           Wo1 + (size_t)k * EMB * 2 * EMB,
                                           Wo2 + (size_t)k * EMB * EMB,
                                           bo1 + (size_t)k * EMB, bo2 + (size_t)k * EMB,
                                           Nr);
    }
}

// Round 8
// 1200.944 us; speedup vs baseline: 3.8086x; 1.1009x over previous
//
#include <hip/hip_runtime.h>

#define EMB   64
#define NCON  50000
#define NVAR  100000
#define NEDGE 1600000
#define EPSLN 1e-5f

// padded-CSR capacities (worst case: every node pads +15)
#define PADEC (NEDGE + 15 * NCON)    // 2,350,000
#define PADEV (NEDGE + 15 * NVAR)    // 3,100,000

typedef _Float16 half2_t __attribute__((ext_vector_type(2)));
typedef _Float16 f16x8  __attribute__((ext_vector_type(8)));

// ---- wave-total via DPP (no DS ops) ----
template <int CTRL, int RMASK>
__device__ __forceinline__ float dpp_add_f(float x) {
    int m = __builtin_amdgcn_update_dpp(0, __builtin_bit_cast(int, x), CTRL, RMASK, 0xf, true);
    return x + __builtin_bit_cast(float, m);
}
__device__ __forceinline__ float wtotal64(float x) {
    x = dpp_add_f<0x111, 0xf>(x);
    x = dpp_add_f<0x112, 0xf>(x);
    x = dpp_add_f<0x114, 0xf>(x);
    x = dpp_add_f<0x118, 0xf>(x);
    x = dpp_add_f<0x142, 0xa>(x);
    x = dpp_add_f<0x143, 0xc>(x);
    return __builtin_bit_cast(float, __builtin_amdgcn_readlane(__builtin_bit_cast(int, x), 63));
}
template <int CTRL, int RMASK>
__device__ __forceinline__ int dpp_add_i(int x) {
    return x + __builtin_amdgcn_update_dpp(0, x, CTRL, RMASK, 0xf, true);
}
__device__ __forceinline__ int wtotal64_i(int x) {
    x = dpp_add_i<0x111, 0xf>(x);
    x = dpp_add_i<0x112, 0xf>(x);
    x = dpp_add_i<0x114, 0xf>(x);
    x = dpp_add_i<0x118, 0xf>(x);
    x = dpp_add_i<0x142, 0xa>(x);
    x = dpp_add_i<0x143, 0xc>(x);
    return __builtin_amdgcn_readlane(x, 63);
}

__device__ __forceinline__ float dot2f(half2_t a, half2_t b, float c) {
    return __builtin_amdgcn_fdot2(a, b, c, false);
}

__device__ __forceinline__ half2_t hmax2(half2_t a, half2_t b) {
#if defined(__has_builtin) && __has_builtin(__builtin_elementwise_max)
    return __builtin_elementwise_max(a, b);
#else
    half2_t r;
    r.x = a.x > b.x ? a.x : b.x;
    r.y = a.y > b.y ? a.y : b.y;
    return r;
#endif
}

// 8 x ds_read_b128 + 32 x v_dot2 with 4 independent accumulator chains
__device__ __forceinline__ float matvec_f16(const _Float16* __restrict__ buf,
                                            const half2_t* __restrict__ wh, float acc) {
    const float4* hp4 = (const float4*)buf;
    float a0 = acc, a1 = 0.0f, a2 = 0.0f, a3 = 0.0f;
#pragma unroll
    for (int j4 = 0; j4 < 8; ++j4) {
        float4 t = hp4[j4];
        a0 = dot2f(wh[4 * j4 + 0], __builtin_bit_cast(half2_t, t.x), a0);
        a1 = dot2f(wh[4 * j4 + 1], __builtin_bit_cast(half2_t, t.y), a1);
        a2 = dot2f(wh[4 * j4 + 2], __builtin_bit_cast(half2_t, t.z), a2);
        a3 = dot2f(wh[4 * j4 + 3], __builtin_bit_cast(half2_t, t.w), a3);
    }
    return (a0 + a1) + (a2 + a3);
}

__device__ __forceinline__ void load_w_f16(const float* __restrict__ W, int stride,
                                           int lane, half2_t* wh) {
#pragma unroll
    for (int j4 = 0; j4 < 16; ++j4) {
        float4 t = *(const float4*)(W + (size_t)lane * stride + j4 * 4);
        wh[2 * j4 + 0] = half2_t{(_Float16)t.x, (_Float16)t.y};
        wh[2 * j4 + 1] = half2_t{(_Float16)t.z, (_Float16)t.w};
    }
}

// ---------------- CSR build ----------------

// both directions in one pass
__global__ __launch_bounds__(256) void hist2_kernel(
        const int* __restrict__ ci, const int* __restrict__ vi,
        int* __restrict__ degC, int* __restrict__ degV, int E) {
    int i = blockIdx.x * blockDim.x + threadIdx.x;
    for (; i < E; i += gridDim.x * blockDim.x) {
        atomicAdd(&degC[ci[i]], 1);
        atomicAdd(&degV[vi[i]], 1);
    }
}

template <bool PAD>
__global__ __launch_bounds__(256) void chunk_sum_kernel(const int* __restrict__ hist,
                                                        int* __restrict__ csum, int N) {
    __shared__ int wpart[4];
    const int base = blockIdx.x * 1024 + threadIdx.x * 4;
    int s = 0;
    if (base + 3 < N) {
        int4 t = *(const int4*)(hist + base);
        if (PAD) s = ((t.x+15)&~15) + ((t.y+15)&~15) + ((t.z+15)&~15) + ((t.w+15)&~15);
        else     s = t.x + t.y + t.z + t.w;
    } else {
#pragma unroll
        for (int j = 0; j < 4; ++j)
            if (base + j < N) { int v = hist[base + j]; s += PAD ? ((v+15)&~15) : v; }
    }
    s = wtotal64_i(s);
    if ((threadIdx.x & 63) == 0) wpart[threadIdx.x >> 6] = s;
    __syncthreads();
    if (threadIdx.x == 0) csum[blockIdx.x] = wpart[0] + wpart[1] + wpart[2] + wpart[3];
}

__global__ void chunk_offsets_kernel(const int* __restrict__ csum, int* __restrict__ coff,
                                     int* __restrict__ rowptr, int nchunk, int N) {
    const int lane = threadIdx.x;
    int carry = 0;
    for (int base = 0; base < nchunk; base += 64) {
        const int i = base + lane;
        int val = (i < nchunk) ? csum[i] : 0;
        int incl = val;
#pragma unroll
        for (int off = 1; off < 64; off <<= 1) {
            int t = __shfl_up(incl, off, 64);
            if (lane >= off) incl += t;
        }
        if (i < nchunk) coff[i] = incl - val + carry;
        carry += __shfl(incl, 63, 64);
    }
    if (lane == 0) rowptr[N] = carry;
}

template <bool PAD>
__global__ __launch_bounds__(256) void chunk_apply_kernel(
        const int* __restrict__ hist, const int* __restrict__ coff,
        int* __restrict__ rowptr, int* __restrict__ cursor, int N) {
    __shared__ int wpart[4];
    const int wv = threadIdx.x >> 6;
    const int lane = threadIdx.x & 63;
    const int base = blockIdx.x * 1024 + threadIdx.x * 4;
    int v0 = 0, v1 = 0, v2 = 0, v3 = 0;
    if (base + 3 < N) {
        int4 t = *(const int4*)(hist + base);
        v0 = t.x; v1 = t.y; v2 = t.z; v3 = t.w;
    } else {
        if (base + 0 < N) v0 = hist[base + 0];
        if (base + 1 < N) v1 = hist[base + 1];
        if (base + 2 < N) v2 = hist[base + 2];
        if (base + 3 < N) v3 = hist[base + 3];
    }
    if (PAD) { v0 = (v0+15)&~15; v1 = (v1+15)&~15; v2 = (v2+15)&~15; v3 = (v3+15)&~15; }
    const int s = v0 + v1 + v2 + v3;
    int incl = s;
#pragma unroll
    for (int off = 1; off < 64; off <<= 1) {
        int t = __shfl_up(incl, off, 64);
        if (lane >= off) incl += t;
    }
    if (lane == 63) wpart[wv] = incl;
    __syncthreads();
    int excl = coff[blockIdx.x] + incl - s;
    for (int w = 0; w < wv; ++w) excl += wpart[w];
    if (base + 0 < N) { rowptr[base + 0] = excl; cursor[base + 0] = excl; excl += v0; }
    if (base + 1 < N) { rowptr[base + 1] = excl; cursor[base + 1] = excl; excl += v1; }
    if (base + 2 < N) { rowptr[base + 2] = excl; cursor[base + 2] = excl; excl += v2; }
    if (base + 3 < N) { rowptr[base + 3] = excl; cursor[base + 3] = excl; excl += v3; }
}

// XCD-bucketed scatter: 8 bucket replicas, each streams ALL edges and writes
// only the edges whose dst falls in its bucket. CSR slots for a dst range are
// contiguous, so each bucket's write region (~2.4-3.1 MB) fits one XCD L2 and
// partial 64B lines combine to full lines before eviction. bucket = blockIdx&7
// aligns replicas with the %8 block->XCD round-robin (locality heuristic only;
// correctness holds under any mapping: each edge written exactly once/direction).
__global__ __launch_bounds__(256) void scatter2_kernel(
        const int* __restrict__ ci, const int* __restrict__ vi,
        const float* __restrict__ ef,
        int* __restrict__ curC, int* __restrict__ curV,
        int2* __restrict__ epC, int2* __restrict__ epV, int E) {
    const int rep = blockIdx.x & 7;
    const int stride = (gridDim.x >> 3) * blockDim.x;
    int i = (blockIdx.x >> 3) * blockDim.x + threadIdx.x;
    for (; i < E; i += stride) {
        const int cd = ci[i];
        const int vd = vi[i];
        const int bC = (int)(((long long)cd * 8) / NCON);
        const int bV = (int)(((long long)vd * 8) / NVAR);
        if (bC == rep) {
            const int slot = atomicAdd(&curC[cd], 1);
            epC[slot] = make_int2(vd, __float_as_int(ef[i]));
        }
        if (bV == rep) {
            const int slot = atomicAdd(&curV[vd], 1);
            epV[slot] = make_int2(cd, __float_as_int(ef[i]));
        }
    }
}

// ---------------- fused node linear: RL segment + LL segment -> f16 ----------------

__global__ __launch_bounds__(256, 4) void lin2_kernel(
        const float* __restrict__ XR, const float* __restrict__ WR,
        const float* __restrict__ bR, _Float16* __restrict__ YR, int NR,
        const float* __restrict__ XL, const float* __restrict__ WL,
        _Float16* __restrict__ YL, int NL, int nbR) {
    __shared__ __align__(16) _Float16 xbuf[4][EMB];
    const int wv = threadIdx.x >> 6;
    const int lane = threadIdx.x & 63;
    const bool isR = (int)blockIdx.x < nbR;
    const float* X = isR ? XR : XL;
    _Float16* Y    = isR ? YR : YL;
    const int N    = isR ? NR : NL;
    const int b0   = isR ? 0 : nbR;
    const int nb   = isR ? nbR : (gridDim.x - nbR);
    half2_t wh[32];
    load_w_f16(isR ? WR : WL, EMB, lane, wh);
    const float bias = isR ? bR[lane] : 0.0f;
    const int nW = nb * 4;
    for (int n = ((int)blockIdx.x - b0) * 4 + wv; n < N; n += nW) {
        xbuf[wv][lane] = (_Float16)X[(size_t)n * EMB + lane];
        Y[(size_t)n * EMB + lane] = (_Float16)matvec_f16(xbuf[wv], wh, bias);
    }
}

// ---------------- edge stage: wave per node, abar accumulate, Wf once/node ----------------
// Key identity: sum_e relu(LN(h_e)) @ Wf^T = (sum_e relu(LN(h_e))) @ Wf^T  (matvec is linear).

__global__ __launch_bounds__(256, 4) void edge_abar_kernel(
        const int* __restrict__ rp16, const int* __restrict__ deg,
        const int2* __restrict__ ep,
        const _Float16* __restrict__ RL, const _Float16* __restrict__ LL,
        const float* __restrict__ We, const float* __restrict__ g1,
        const float* __restrict__ b1, const float* __restrict__ Wf,
        const float* __restrict__ bfp, _Float16* __restrict__ AGG, int Nr) {
    __shared__ __align__(16) _Float16 abuf[4][EMB];
    const int wv   = threadIdx.x >> 6;
    const int lane = threadIdx.x & 63;
    const int col  = lane & 15;
    const int quad = lane >> 4;
    const int kb   = quad * 8;

    half2_t weh[8], gkh[8], bkh[8];
#pragma unroll
    for (int j = 0; j < 4; ++j) {
        weh[j]     = half2_t{(_Float16)We[kb + 2*j],      (_Float16)We[kb + 2*j + 1]};
        weh[4 + j] = half2_t{(_Float16)We[kb + 32 + 2*j], (_Float16)We[kb + 32 + 2*j + 1]};
        gkh[j]     = half2_t{(_Float16)g1[kb + 2*j],      (_Float16)g1[kb + 2*j + 1]};
        gkh[4 + j] = half2_t{(_Float16)g1[kb + 32 + 2*j], (_Float16)g1[kb + 32 + 2*j + 1]};
        bkh[j]     = half2_t{(_Float16)b1[kb + 2*j],      (_Float16)b1[kb + 2*j + 1]};
        bkh[4 + j] = half2_t{(_Float16)b1[kb + 32 + 2*j], (_Float16)b1[kb + 32 + 2*j + 1]};
    }
    half2_t whF[32];
    load_w_f16(Wf, EMB, lane, whF);
    const float bfv = bfp[lane];

    const int nW = gridDim.x * 4;
    for (int n = blockIdx.x * 4 + wv; n < Nr; n += nW) {
        const int g0  = rp16[n] >> 4;
        const int g1e = rp16[n + 1] >> 4;
        const int dn  = deg[n];
        half2_t rl2[8];
        *(f16x8*)&rl2[0] = *(const f16x8*)(RL + (size_t)n * EMB + kb);
        *(f16x8*)&rl2[4] = *(const f16x8*)(RL + (size_t)n * EMB + kb + 32);
        float acc[16];
#pragma unroll
        for (int j = 0; j < 16; ++j) acc[j] = 0.0f;

        if (g0 < g1e) {
            // prefetch first group
            bool livN = col < dn;
            int2 p = ep[(g0 << 4) + col];
            int sN = livN ? p.x : 0;
            float fN = livN ? __int_as_float(p.y) : 0.0f;
            f16x8 llaN = *(const f16x8*)(LL + (size_t)sN * EMB + kb);
            f16x8 llbN = *(const f16x8*)(LL + (size_t)sN * EMB + kb + 32);

            for (int g = g0; g < g1e; ++g) {
                const bool liv = livN;
                const float f = fN;
                half2_t h2[8];
                *(f16x8*)&h2[0] = llaN;
                *(f16x8*)&h2[4] = llbN;
                if (g + 1 < g1e) {
                    const int cnt = dn - ((g + 1 - g0) << 4);
                    livN = col < cnt;
                    p = ep[((g + 1) << 4) + col];
                    const int s2 = livN ? p.x : 0;
                    fN = livN ? __int_as_float(p.y) : 0.0f;
                    llaN = *(const f16x8*)(LL + (size_t)s2 * EMB + kb);
                    llbN = *(const f16x8*)(LL + (size_t)s2 * EMB + kb + 32);
                }
                const _Float16 fh = (_Float16)f;
                const half2_t f2 = half2_t{fh, fh};
                const half2_t one2 = half2_t{(_Float16)1.0f, (_Float16)1.0f};
                float ps = 0.0f, pq = 0.0f;
#pragma unroll
                for (int j = 0; j < 8; ++j) {
                    h2[j] = (h2[j] + rl2[j]) + f2 * weh[j];
                    ps = dot2f(h2[j], one2, ps);
                    pq = dot2f(h2[j], h2[j], pq);
                }
                ps += __shfl_xor(ps, 16, 64); ps += __shfl_xor(ps, 32, 64);
                pq += __shfl_xor(pq, 16, 64); pq += __shfl_xor(pq, 32, 64);
                const float mean = ps * (1.0f / EMB);
                const float var  = pq * (1.0f / EMB) - mean * mean;
                const float rs   = rsqrtf(var + EPSLN);
                const _Float16 rsh = (_Float16)rs;
                const _Float16 mnh = (_Float16)mean;
                const half2_t rs2 = half2_t{rsh, rsh};
                const half2_t mn2 = half2_t{mnh, mnh};
                const half2_t z2  = half2_t{(_Float16)0.0f, (_Float16)0.0f};
                if (liv) {
#pragma unroll
                    for (int j = 0; j < 8; ++j) {
                        const half2_t sc = gkh[j] * rs2;
                        half2_t a = (h2[j] - mn2) * sc + bkh[j];
                        a = hmax2(a, z2);
                        acc[2*j]   += (float)a.x;
                        acc[2*j+1] += (float)a.y;
                    }
                }
            }
        }
        // reduce abar partials across the 16 cols of each quad
#pragma unroll
        for (int st = 1; st < 16; st <<= 1) {
#pragma unroll
            for (int j = 0; j < 16; ++j)
                acc[j] += __shfl_xor(acc[j], st, 64);
        }
        // lane's element of abar: acc[col] maps to k = (col<8) ? kb+col : kb+32+(col-8)
        abuf[wv][(col < 8) ? (kb + col) : (kb + 24 + col)] = (_Float16)acc[col];
        // agg = abar @ Wf^T + deg*bf   (one matvec per node)
        AGG[(size_t)n * EMB + lane] = (_Float16)matvec_f16(abuf[wv], whF, (float)dn * bfv);
    }
}

// ---------------- fallback edge path (wave per node, dot2, f16 RL/LL) ----------------

__global__ __launch_bounds__(256, 4) void edge_csr_kernel(
        const int* __restrict__ rowptr, const int2* __restrict__ ep,
        const _Float16* __restrict__ RL, const _Float16* __restrict__ LL,
        const float* __restrict__ Wecol, const float* __restrict__ g1,
        const float* __restrict__ b1,
        const float* __restrict__ Wf, const float* __restrict__ bfp,
        _Float16* __restrict__ AGG, int Nr) {
    __shared__ __align__(16) _Float16 hbuf[4][EMB];
    const int wv = threadIdx.x >> 6;
    const int lane = threadIdx.x & 63;
    half2_t wh[32];
    load_w_f16(Wf, EMB, lane, wh);
    const float we  = Wecol[lane];
    const float g   = g1[lane];
    const float bb  = b1[lane];
    const float bf_ = bfp[lane];
    const int nW = gridDim.x * 4;
    for (int n = blockIdx.x * 4 + wv; n < Nr; n += nW) {
        const int beg = rowptr[n];
        const int end = rowptr[n + 1];
        const float rl = (float)RL[(size_t)n * EMB + lane];
        float acc = 0.0f;
        for (int idx = beg; idx < end; ++idx) {
            const int2 p = ep[idx];
            const float f = __int_as_float(p.y);
            float h = rl + (float)LL[(size_t)p.x * EMB + lane] + f * we;
            const float s1 = wtotal64(h);
            const float s2 = wtotal64(h * h);
            const float m   = s1 * (1.0f / EMB);
            const float var = s2 * (1.0f / EMB) - m * m;
            float hn = fmaxf((h - m) * rsqrtf(var + EPSLN) * g + bb, 0.0f);
            hbuf[wv][lane] = (_Float16)hn;
            acc = matvec_f16(hbuf[wv], wh, acc);
        }
        AGG[(size_t)n * EMB + lane] = (_Float16)(acc + (float)(end - beg) * bf_);
    }
}

// ---------------- fused output MLP ----------------
// z = LN(AGG); o = relu(Wo1a@z + Wo1b@right + bo1); right += Wo2@o + bo2

__global__ __launch_bounds__(256, 3) void out_kernel(
        const _Float16* __restrict__ AGG, float* __restrict__ right,
        const float* __restrict__ g2, const float* __restrict__ b2,
        const float* __restrict__ Wo1, const float* __restrict__ Wo2,
        const float* __restrict__ bo1, const float* __restrict__ bo2, int N) {
    __shared__ __align__(16) _Float16 zbuf[4][EMB];
    __shared__ __align__(16) _Float16 rbuf[4][EMB];
    __shared__ __align__(16) _Float16 obuf[4][EMB];
    const int wv = threadIdx.x >> 6;
    const int lane = threadIdx.x & 63;
    half2_t wh1[32], whB[32], wh2[32];
    load_w_f16(Wo1, 2 * EMB, lane, wh1);            // Wo1[:, 0:64]
    load_w_f16(Wo1 + EMB, 2 * EMB, lane, whB);      // Wo1[:, 64:128]
    load_w_f16(Wo2, EMB, lane, wh2);
    const float g    = g2[lane];
    const float bb   = b2[lane];
    const float bo1v = bo1[lane];
    const float bo2v = bo2[lane];
    const int nW = gridDim.x * 4;
    for (int n = blockIdx.x * 4 + wv; n < N; n += nW) {
        const float a = (float)AGG[(size_t)n * EMB + lane];
        const float rf = right[(size_t)n * EMB + lane];
        const float s1 = wtotal64(a);
        const float s2 = wtotal64(a * a);
        const float m   = s1 * (1.0f / EMB);
        const float var = s2 * (1.0f / EMB) - m * m;
        const float z = (a - m) * rsqrtf(var + EPSLN) * g + bb;
        zbuf[wv][lane] = (_Float16)z;
        rbuf[wv][lane] = (_Float16)rf;
        float acc = matvec_f16(zbuf[wv], wh1, bo1v);
        acc = matvec_f16(rbuf[wv], whB, acc);
        obuf[wv][lane] = (_Float16)fmaxf(acc, 0.0f);
        float acc2 = matvec_f16(obuf[wv], wh2, bo2v);
        right[(size_t)n * EMB + lane] = rf + acc2;
    }
}

extern "C" void kernel_launch(void* const* d_in, const int* in_sizes, int n_in,
                              void* d_out, int out_size, void* d_ws, size_t ws_size,
                              hipStream_t stream) {
    const float* cf  = (const float*)d_in[0];
    const float* vfp = (const float*)d_in[1];
    const int*   ei  = (const int*)d_in[2];
    const float* ef  = (const float*)d_in[3];
    const float* Wl  = (const float*)d_in[4];
    const float* bl  = (const float*)d_in[5];
    const float* We  = (const float*)d_in[6];
    const float* Wr  = (const float*)d_in[7];
    const float* g1  = (const float*)d_in[8];
    const float* b1  = (const float*)d_in[9];
    const float* Wf  = (const float*)d_in[10];
    const float* bfp = (const float*)d_in[11];
    const float* g2  = (const float*)d_in[12];
    const float* b2  = (const float*)d_in[13];
    const float* Wo1 = (const float*)d_in[14];
    const float* bo1 = (const float*)d_in[15];
    const float* Wo2 = (const float*)d_in[16];
    const float* bo2 = (const float*)d_in[17];

    float* c = (float*)d_out;
    float* v = c + (size_t)NCON * EMB;
    (void)hipMemcpyAsync(c, cf,  (size_t)NCON * EMB * sizeof(float), hipMemcpyDeviceToDevice, stream);
    (void)hipMemcpyAsync(v, vfp, (size_t)NVAR * EMB * sizeof(float), hipMemcpyDeviceToDevice, stream);

    float* wsf = (float*)d_ws;
    size_t off = 0;
    _Float16* AGG = (_Float16*)(wsf + off); off += (size_t)NVAR * EMB / 2;  // f16
    _Float16* RL  = (_Float16*)(wsf + off); off += (size_t)NVAR * EMB / 2;  // f16
    _Float16* LL  = (_Float16*)(wsf + off); off += (size_t)NVAR * EMB / 2;  // f16
    int* degC  = (int*)(wsf + off); off += NCON;
    int* degV  = (int*)(wsf + off); off += NVAR;
    int* rp16C = (int*)(wsf + off); off += NCON + 4;
    int* curC  = (int*)(wsf + off); off += NCON;
    int* rp16V = (int*)(wsf + off); off += NVAR + 4;
    int* curV  = (int*)(wsf + off); off += NVAR;
    int* csumC = (int*)(wsf + off); off += 128;
    int* coffC = (int*)(wsf + off); off += 128;
    int* csumV = (int*)(wsf + off); off += 128;
    int* coffV = (int*)(wsf + off); off += 128;
    size_t off_edges = off;
    int2* epC = (int2*)(wsf + off); off += (size_t)2 * PADEC;
    int2* epV = (int2*)(wsf + off); off += (size_t)2 * PADEV;
    const bool use_mfma = ws_size >= off * sizeof(float);
    if (!use_mfma) {
        off = off_edges;
        epC = (int2*)(wsf + off); off += (size_t)2 * NEDGE;
        epV = (int2*)(wsf + off); off += (size_t)2 * NEDGE;
    }

    const int* ci = ei;
    const int* vi = ei + NEDGE;

    const dim3 blk(256);
    const int NB = 2048;
    const int NBL = 1536;
    const int nchC = (NCON + 1023) / 1024;   // 49
    const int nchV = (NVAR + 1023) / 1024;   // 98

    (void)hipMemsetAsync(degC, 0, NCON * sizeof(int), stream);
    (void)hipMemsetAsync(degV, 0, NVAR * sizeof(int), stream);
    hist2_kernel<<<1024, blk, 0, stream>>>(ci, vi, degC, degV, NEDGE);
    if (use_mfma) {
        chunk_sum_kernel<true><<<nchC, blk, 0, stream>>>(degC, csumC, NCON);
        chunk_sum_kernel<true><<<nchV, blk, 0, stream>>>(degV, csumV, NVAR);
        chunk_offsets_kernel<<<1, 64, 0, stream>>>(csumC, coffC, rp16C, nchC, NCON);
        chunk_offsets_kernel<<<1, 64, 0, stream>>>(csumV, coffV, rp16V, nchV, NVAR);
        chunk_apply_kernel<true><<<nchC, blk, 0, stream>>>(degC, coffC, rp16C, curC, NCON);
        chunk_apply_kernel<true><<<nchV, blk, 0, stream>>>(degV, coffV, rp16V, curV, NVAR);
    } else {
        chunk_sum_kernel<false><<<nchC, blk, 0, stream>>>(degC, csumC, NCON);
        chunk_sum_kernel<false><<<nchV, blk, 0, stream>>>(degV, csumV, NVAR);
        chunk_offsets_kernel<<<1, 64, 0, stream>>>(csumC, coffC, rp16C, nchC, NCON);
        chunk_offsets_kernel<<<1, 64, 0, stream>>>(csumV, coffV, rp16V, nchV, NVAR);
        chunk_apply_kernel<false><<<nchC, blk, 0, stream>>>(degC, coffC, rp16C, curC, NCON);
        chunk_apply_kernel<false><<<nchV, blk, 0, stream>>>(degV, coffV, rp16V, curV, NVAR);
    }
    scatter2_kernel<<<2048, blk, 0, stream>>>(ci, vi, ef, curC, curV, epC, epV, NEDGE);

    for (int k = 0; k < 4; ++k) {
        const bool v2c = ((k & 1) == 0);
        float* right   = v2c ? c : v;
        float* left    = v2c ? v : c;
        const int Nr   = v2c ? NCON : NVAR;
        const int Nl   = v2c ? NVAR : NCON;
        const int nbR  = v2c ? NBL / 3 : 2 * NBL / 3;   // split blocks ~ Nr : Nl

        lin2_kernel<<<NBL, blk, 0, stream>>>(
            right, Wl + (size_t)k * EMB * EMB, bl + (size_t)k * EMB, RL, Nr,
            left,  Wr + (size_t)k * EMB * EMB, LL, Nl, nbR);

        if (use_mfma) {
            edge_abar_kernel<<<NB, blk, 0, stream>>>(
                v2c ? rp16C : rp16V, v2c ? degC : degV, v2c ? epC : epV,
                RL, LL, We + (size_t)k * EMB,
                g1 + (size_t)k * EMB, b1 + (size_t)k * EMB,
                Wf + (size_t)k * EMB * EMB, bfp + (size_t)k * EMB, AGG, Nr);
        } else {
            edge_csr_kernel<<<NB, blk, 0, stream>>>(
                v2c ? rp16C : rp16V, v2c ? epC : epV,
                RL, LL, We + (size_t)k * EMB,
                g1 + (size_t)k * EMB, b1 + (size_t)k * EMB,
                Wf + (size_t)k * EMB * EMB, bfp + (size_t)k * EMB, AGG, Nr);
        }
        out_kernel<<<NB, blk, 0, stream>>>(AGG, right,
                                           g2 + (size_t)k * EMB, b2 + (size_t)k * EMB,
                                           Wo1 + (size_t)k * EMB * 2 * EMB,
                                           Wo2 + (size_t)k * EMB * EMB,
                                           bo1 + (size_t)k * EMB, bo2 + (size_t)k * EMB,
                                           Nr);
    }
}